// Round 1
// baseline (1145.912 us; speedup 1.0000x reference)
//
#include <hip/hip_runtime.h>
#include <hip/hip_bf16.h>

// DoubleSAGE link predictor, restructured:
//   z1 = x @ [W_self1 | W_neigh1]          (bf16 MFMA GEMM, N=512)
//   h1 = relu(z1_self + CSR-mean(z1_neigh) + b1)
//   z2 = h1 @ [W_self2 | W_neigh2]         (N=128)
//   h2 = z2_self + CSR-mean(z2_neigh) + b2
//   UV = h2 @ [Wp1_top | Wp1_bot]          (N=128, fp32 out)
//   score(s,d) = relu(UV[s][:64] + UV[d][64:] + bp1) . Wp2 + bp2
// All aggregation via CSR built per-call (atomic histogram + scan + fill).

#define N_NODES 100000
#define N_EDGES 1000000
#define EPOS    200000

typedef unsigned short u16;
typedef unsigned int   u32;

typedef __bf16 bf16x8 __attribute__((ext_vector_type(8)));
typedef float  f32x4  __attribute__((ext_vector_type(4)));
typedef u16    u16x8  __attribute__((ext_vector_type(8)));

__device__ __forceinline__ u16 f2bf(float f) {
  u32 u = __float_as_uint(f);
  u32 r = (u + 0x7fffu + ((u >> 16) & 1u)) >> 16;   // RNE
  return (u16)r;
}
__device__ __forceinline__ float bf2f(u16 h) {
  return __uint_as_float(((u32)h) << 16);
}

// ---------------------------------------------------------------- convert x
__global__ __launch_bounds__(256) void k_x2bf(const float* __restrict__ in,
                                              u16* __restrict__ out) {
  long i = ((long)blockIdx.x * 256 + threadIdx.x) * 8;
  float4 f0 = *(const float4*)(in + i);
  float4 f1 = *(const float4*)(in + i + 4);
  u16x8 o;
  o[0] = f2bf(f0.x); o[1] = f2bf(f0.y); o[2] = f2bf(f0.z); o[3] = f2bf(f0.w);
  o[4] = f2bf(f1.x); o[5] = f2bf(f1.y); o[6] = f2bf(f1.z); o[7] = f2bf(f1.w);
  *(u16x8*)(out + i) = o;
}

// ------------------------------------------------------- weight repack (B^T)
// W1t[j][k] (j<512, k<512): j<256 -> W_self1[k][j], else W_neigh1[k][j-256]
__global__ void k_w1t(const float* __restrict__ Ws, const float* __restrict__ Wn,
                      u16* __restrict__ W1t) {
  int idx = blockIdx.x * 256 + threadIdx.x;   // < 512*512
  int j = idx >> 9, k = idx & 511;
  float v = (j < 256) ? Ws[k * 256 + j] : Wn[k * 256 + (j - 256)];
  W1t[idx] = f2bf(v);
}
__global__ void k_w2t(const float* __restrict__ Ws, const float* __restrict__ Wn,
                      u16* __restrict__ W2t) {
  int idx = blockIdx.x * 256 + threadIdx.x;   // < 128*256
  int j = idx >> 8, k = idx & 255;
  float v = (j < 64) ? Ws[k * 64 + j] : Wn[k * 64 + (j - 64)];
  W2t[idx] = f2bf(v);
}
// Wpt[j][k] (j<128, k<64): j<64 -> Wp1[k][j] (U), else Wp1[64+k][j-64] (V)
__global__ void k_wpt(const float* __restrict__ Wp1, u16* __restrict__ Wpt) {
  int idx = blockIdx.x * 256 + threadIdx.x;   // < 128*64
  int j = idx >> 6, k = idx & 63;
  float v = (j < 64) ? Wp1[k * 64 + j] : Wp1[(64 + k) * 64 + (j - 64)];
  Wpt[idx] = f2bf(v);
}

// ---------------------------------------------------------------- CSR build
__global__ void k_deg(const int* __restrict__ dst, int* __restrict__ deg) {
  int i = blockIdx.x * 256 + threadIdx.x;
  if (i < N_EDGES) atomicAdd(&deg[dst[i]], 1);
}

__global__ __launch_bounds__(1024) void k_scan(const int* __restrict__ deg,
                                               int* __restrict__ offs,
                                               float* __restrict__ invdeg) {
  __shared__ int ps[1024];
  const int t  = threadIdx.x;
  const int C  = (N_NODES + 1023) / 1024;   // 98
  const int lo = t * C;
  const int hi = min(lo + C, N_NODES);
  int s = 0;
  for (int i = lo; i < hi; ++i) s += deg[i];
  ps[t] = s;
  __syncthreads();
  for (int off = 1; off < 1024; off <<= 1) {
    int v = (t >= off) ? ps[t - off] : 0;
    __syncthreads();
    ps[t] += v;
    __syncthreads();
  }
  int run = ps[t] - s;                       // exclusive prefix
  for (int i = lo; i < hi; ++i) {
    offs[i] = run;
    int d = deg[i];
    run += d;
    invdeg[i] = 1.0f / (float)(d > 0 ? d : 1);
  }
  if (t == 0) offs[N_NODES] = N_EDGES;
}

__global__ void k_fill(const int* __restrict__ src, const int* __restrict__ dst,
                       const int* __restrict__ offs, int* __restrict__ cur,
                       int* __restrict__ csr) {
  int i = blockIdx.x * 256 + threadIdx.x;
  if (i < N_EDGES) {
    int d = dst[i];
    int p = atomicAdd(&cur[d], 1);
    csr[offs[d] + p] = src[i];
  }
}

// ------------------------------------------------------------- bf16 MFMA GEMM
// C[M,N] = A[M,K] @ Bt[N,K]^T   (A,Bt bf16 row-major; C bf16 or f32)
// 128x128 tile, 4 waves (each 64x64 = 4x4 frags of 16x16x32), BK=32,
// reg-staged LDS, next-tile prefetch into registers.
template <bool OUT_F32>
__global__ __launch_bounds__(256) void gemm_bt(const u16* __restrict__ A,
                                               const u16* __restrict__ Bt,
                                               void* __restrict__ Cv,
                                               int M, int N, int K) {
  __shared__ u16 As[128 * 32];
  __shared__ u16 Bs[128 * 32];
  const int tid  = threadIdx.x;
  const int lane = tid & 63;
  const int wid  = tid >> 6;
  const int wr   = wid >> 1, wc = wid & 1;
  const int bm0  = blockIdx.x * 128;
  const int bn0  = blockIdx.y * 128;

  const int sr = tid >> 2;          // staging row 0..63 (and +64)
  const int sc = (tid & 3) * 8;     // staging col (bf16 units)
  const long ar0 = (long)min(bm0 + sr,      M - 1) * K + sc;
  const long ar1 = (long)min(bm0 + sr + 64, M - 1) * K + sc;
  const long br0 = (long)(bn0 + sr)      * K + sc;
  const long br1 = (long)(bn0 + sr + 64) * K + sc;

  f32x4 acc[4][4];
#pragma unroll
  for (int i = 0; i < 4; ++i)
#pragma unroll
    for (int j = 0; j < 4; ++j) {
      f32x4 z = {0.f, 0.f, 0.f, 0.f};
      acc[i][j] = z;
    }

  uint4 a0 = *(const uint4*)(A + ar0);
  uint4 a1 = *(const uint4*)(A + ar1);
  uint4 b0 = *(const uint4*)(Bt + br0);
  uint4 b1 = *(const uint4*)(Bt + br1);

  const int nk = K >> 5;
  for (int kk = 0; kk < nk; ++kk) {
    *(uint4*)&As[sr * 32 + sc]        = a0;
    *(uint4*)&As[(sr + 64) * 32 + sc] = a1;
    *(uint4*)&Bs[sr * 32 + sc]        = b0;
    *(uint4*)&Bs[(sr + 64) * 32 + sc] = b1;
    __syncthreads();
    if (kk + 1 < nk) {
      const int k0 = (kk + 1) << 5;
      a0 = *(const uint4*)(A + ar0 + k0);
      a1 = *(const uint4*)(A + ar1 + k0);
      b0 = *(const uint4*)(Bt + br0 + k0);
      b1 = *(const uint4*)(Bt + br1 + k0);
    }
    bf16x8 af[4], bfr[4];
#pragma unroll
    for (int mi = 0; mi < 4; ++mi)
      af[mi] = *reinterpret_cast<const bf16x8*>(
          &As[(wr * 64 + mi * 16 + (lane & 15)) * 32 + ((lane >> 4) * 8)]);
#pragma unroll
    for (int ni = 0; ni < 4; ++ni)
      bfr[ni] = *reinterpret_cast<const bf16x8*>(
          &Bs[(wc * 64 + ni * 16 + (lane & 15)) * 32 + ((lane >> 4) * 8)]);
#pragma unroll
    for (int mi = 0; mi < 4; ++mi)
#pragma unroll
      for (int ni = 0; ni < 4; ++ni)
        acc[mi][ni] = __builtin_amdgcn_mfma_f32_16x16x32_bf16(
            af[mi], bfr[ni], acc[mi][ni], 0, 0, 0);
    __syncthreads();
  }

  // epilogue: C layout col = lane&15, row = (lane>>4)*4 + e   [m89-verified]
  const int colb = bn0 + wc * 64 + (lane & 15);
  const int rowb = bm0 + wr * 64 + ((lane >> 4) * 4);
#pragma unroll
  for (int mi = 0; mi < 4; ++mi) {
#pragma unroll
    for (int ni = 0; ni < 4; ++ni) {
      const int col = colb + ni * 16;
#pragma unroll
      for (int e = 0; e < 4; ++e) {
        const int row = rowb + mi * 16 + e;
        if (row < M) {
          if (OUT_F32)
            ((float*)Cv)[(long)row * N + col] = acc[mi][ni][e];
          else
            ((u16*)Cv)[(long)row * N + col] = f2bf(acc[mi][ni][e]);
        }
      }
    }
  }
}

// ------------------------------------------------------------- aggregation
// h1 = relu(z1_self + mean(z1_neigh over in-edges) + b1)  -> bf16 [N,256]
__global__ __launch_bounds__(256) void k_agg1(const u16* __restrict__ z1b,
                                              const int* __restrict__ csr,
                                              const int* __restrict__ offs,
                                              const float* __restrict__ invdeg,
                                              const float* __restrict__ b1,
                                              u16* __restrict__ h1b) {
  const int v = blockIdx.x;
  const int c = threadIdx.x;
  const int o0 = offs[v], o1 = offs[v + 1];
  float acc = 0.f;
  for (int i = o0; i < o1; ++i) {
    const int u = csr[i];
    acc += bf2f(z1b[(long)u * 512 + 256 + c]);
  }
  float h = bf2f(z1b[(long)v * 512 + c]) + acc * invdeg[v] + b1[c];
  h1b[(long)v * 256 + c] = f2bf(fmaxf(h, 0.f));
}

// h2 = z2_self + mean(z2_neigh) + b2  (no relu) -> bf16 [N,64]
__global__ __launch_bounds__(256) void k_agg2(const u16* __restrict__ z2b,
                                              const int* __restrict__ csr,
                                              const int* __restrict__ offs,
                                              const float* __restrict__ invdeg,
                                              const float* __restrict__ b2,
                                              u16* __restrict__ h2b) {
  const int v = blockIdx.x * 4 + (threadIdx.x >> 6);
  const int c = threadIdx.x & 63;
  const int o0 = offs[v], o1 = offs[v + 1];
  float acc = 0.f;
  for (int i = o0; i < o1; ++i) {
    const int u = csr[i];
    acc += bf2f(z2b[(long)u * 128 + 64 + c]);
  }
  float h = bf2f(z2b[(long)v * 128 + c]) + acc * invdeg[v] + b2[c];
  h2b[(long)v * 64 + c] = f2bf(h);
}

// ------------------------------------------------------------- edge scoring
__global__ __launch_bounds__(256) void k_edge(const float* __restrict__ UV,
                                              const int* __restrict__ ps,
                                              const int* __restrict__ pd,
                                              const int* __restrict__ ns,
                                              const int* __restrict__ nd,
                                              const float* __restrict__ bp1,
                                              const float* __restrict__ Wp2,
                                              const float* __restrict__ bp2,
                                              float* __restrict__ out) {
  const int g = blockIdx.x * 4 + (threadIdx.x >> 6);   // edge id 0..399999
  const int j = threadIdx.x & 63;
  int s, d;
  if (g < EPOS) { s = ps[g]; d = pd[g]; }
  else          { s = ns[g - EPOS]; d = nd[g - EPOS]; }
  float t = UV[(long)s * 128 + j] + UV[(long)d * 128 + 64 + j] + bp1[j];
  float r = fmaxf(t, 0.f) * Wp2[j];
#pragma unroll
  for (int off = 32; off > 0; off >>= 1) r += __shfl_down(r, off, 64);
  if (j == 0) out[g] = r + bp2[0];
}

// ---------------------------------------------------------------- launcher
extern "C" void kernel_launch(void* const* d_in, const int* in_sizes, int n_in,
                              void* d_out, int out_size, void* d_ws, size_t ws_size,
                              hipStream_t stream) {
  const float* x   = (const float*)d_in[0];
  const int*   src = (const int*)d_in[1];
  const int*   dst = (const int*)d_in[2];
  const int*   ps  = (const int*)d_in[3];
  const int*   pd  = (const int*)d_in[4];
  const int*   ns  = (const int*)d_in[5];
  const int*   nd  = (const int*)d_in[6];
  const float* Ws1 = (const float*)d_in[7];
  const float* Wn1 = (const float*)d_in[8];
  const float* b1  = (const float*)d_in[9];
  const float* Ws2 = (const float*)d_in[10];
  const float* Wn2 = (const float*)d_in[11];
  const float* b2  = (const float*)d_in[12];
  const float* Wp1 = (const float*)d_in[13];
  const float* bp1 = (const float*)d_in[14];
  const float* Wp2 = (const float*)d_in[15];
  const float* bp2 = (const float*)d_in[16];
  float* out = (float*)d_out;

  // workspace layout (~211 MB), regions reused across phases:
  //  region A [0, 102.4MB):   xb (GEMM1 in) -> h1b (+0) , UV (+51.2MB)
  //  region B [102.4, 204.8): z1b -> z2b (+0), h2b (+25.6MB)
  //  region C [204.8, ~211):  W1t, W2t, Wpt, deg, cur, offs, invdeg, csr
  char* ws = (char*)d_ws;
  const size_t RB = 102400000;
  const size_t RC = 204800000;
  u16*   xb  = (u16*)(ws);
  u16*   h1b = (u16*)(ws);                    // alias: xb dead after GEMM1
  float* UV  = (float*)(ws + 51200000);
  u16*   z1b = (u16*)(ws + RB);
  u16*   z2b = (u16*)(ws + RB);               // alias: z1b dead after agg1
  u16*   h2b = (u16*)(ws + RB + 25600000);
  size_t o = RC;
  u16*   W1t = (u16*)(ws + o); o += 524288;
  u16*   W2t = (u16*)(ws + o); o += 65536;
  u16*   Wpt = (u16*)(ws + o); o += 16384;
  int*   deg = (int*)(ws + o); o += 400128;
  int*   cur = (int*)(ws + o); o += 400128;
  int*   offs= (int*)(ws + o); o += 400128;
  float* idg = (float*)(ws + o); o += 400128;
  int*   csr = (int*)(ws + o); o += 4000000;
  (void)ws_size; (void)in_sizes; (void)n_in; (void)out_size;

  hipMemsetAsync(deg, 0, 400128 * 2, stream);   // deg + cur contiguous

  k_x2bf<<<25000, 256, 0, stream>>>(x, xb);
  k_w1t<<<1024, 256, 0, stream>>>(Ws1, Wn1, W1t);
  k_w2t<<<128, 256, 0, stream>>>(Ws2, Wn2, W2t);
  k_wpt<<<32, 256, 0, stream>>>(Wp1, Wpt);
  k_deg<<<3907, 256, 0, stream>>>(dst, deg);
  k_scan<<<1, 1024, 0, stream>>>(deg, offs, idg);
  k_fill<<<3907, 256, 0, stream>>>(src, dst, offs, cur, csr);

  gemm_bt<false><<<dim3(782, 4), 256, 0, stream>>>(xb, W1t, z1b, N_NODES, 512, 512);
  k_agg1<<<100000, 256, 0, stream>>>(z1b, csr, offs, idg, b1, h1b);
  gemm_bt<false><<<dim3(782, 1), 256, 0, stream>>>(h1b, W2t, z2b, N_NODES, 128, 256);
  k_agg2<<<25000, 256, 0, stream>>>(z2b, csr, offs, idg, b2, h2b);
  gemm_bt<true><<<dim3(782, 1), 256, 0, stream>>>(h2b, Wpt, UV, N_NODES, 128, 64);
  k_edge<<<100000, 256, 0, stream>>>(UV, ps, pd, ns, nd, bp1, Wp2, bp2, out);
}

// Round 2
// 774.476 us; speedup vs baseline: 1.4796x; 1.4796x over previous
//
#include <hip/hip_runtime.h>
#include <hip/hip_bf16.h>

// DoubleSAGE link predictor, restructured:
//   z1 = x @ [W_self1 | W_neigh1]          (bf16 MFMA GEMM, N=512)
//   h1 = relu(z1_self + CSR-mean(z1_neigh) + b1)
//   z2 = h1 @ [W_self2 | W_neigh2]         (N=128)
//   h2 = z2_self + CSR-mean(z2_neigh) + b2
//   UV = h2 @ [Wp1_top | Wp1_bot]          (N=128, fp32 out)
//   score(s,d) = relu(UV[s][:64] + UV[d][64:] + bp1) . Wp2 + bp2
// CSR built per-call: atomic histogram (records slot) + 3-phase parallel
// scan + non-atomic fill.

#define N_NODES 100000
#define N_EDGES 1000000
#define EPOS    200000
#define NSB     391        // ceil(N_NODES/256) scan blocks

typedef unsigned short u16;
typedef unsigned int   u32;

typedef __bf16 bf16x8 __attribute__((ext_vector_type(8)));
typedef float  f32x4  __attribute__((ext_vector_type(4)));
typedef u16    u16x8  __attribute__((ext_vector_type(8)));

__device__ __forceinline__ u16 f2bf(float f) {
  u32 u = __float_as_uint(f);
  u32 r = (u + 0x7fffu + ((u >> 16) & 1u)) >> 16;   // RNE
  return (u16)r;
}
__device__ __forceinline__ float bf2f(u16 h) {
  return __uint_as_float(((u32)h) << 16);
}

// ---------------------------------------------------------------- convert x
__global__ __launch_bounds__(256) void k_x2bf(const float* __restrict__ in,
                                              u16* __restrict__ out) {
  long i = ((long)blockIdx.x * 256 + threadIdx.x) * 8;
  float4 f0 = *(const float4*)(in + i);
  float4 f1 = *(const float4*)(in + i + 4);
  u16x8 o;
  o[0] = f2bf(f0.x); o[1] = f2bf(f0.y); o[2] = f2bf(f0.z); o[3] = f2bf(f0.w);
  o[4] = f2bf(f1.x); o[5] = f2bf(f1.y); o[6] = f2bf(f1.z); o[7] = f2bf(f1.w);
  *(u16x8*)(out + i) = o;
}

// ------------------------------------------------------- weight repack (B^T)
__global__ void k_w1t(const float* __restrict__ Ws, const float* __restrict__ Wn,
                      u16* __restrict__ W1t) {
  int idx = blockIdx.x * 256 + threadIdx.x;   // < 512*512
  int j = idx >> 9, k = idx & 511;
  float v = (j < 256) ? Ws[k * 256 + j] : Wn[k * 256 + (j - 256)];
  W1t[idx] = f2bf(v);
}
__global__ void k_w2t(const float* __restrict__ Ws, const float* __restrict__ Wn,
                      u16* __restrict__ W2t) {
  int idx = blockIdx.x * 256 + threadIdx.x;   // < 128*256
  int j = idx >> 8, k = idx & 255;
  float v = (j < 64) ? Ws[k * 64 + j] : Wn[k * 64 + (j - 64)];
  W2t[idx] = f2bf(v);
}
__global__ void k_wpt(const float* __restrict__ Wp1, u16* __restrict__ Wpt) {
  int idx = blockIdx.x * 256 + threadIdx.x;   // < 128*64
  int j = idx >> 6, k = idx & 63;
  float v = (j < 64) ? Wp1[k * 64 + j] : Wp1[(64 + k) * 64 + (j - 64)];
  Wpt[idx] = f2bf(v);
}

// ---------------------------------------------------------------- CSR build
// histogram; also record each edge's slot within its dst bucket (kills the
// second atomic pass)
__global__ void k_deg(const int* __restrict__ dst, int* __restrict__ deg,
                      int* __restrict__ epos) {
  int i = blockIdx.x * 256 + threadIdx.x;
  if (i < N_EDGES) epos[i] = atomicAdd(&deg[dst[i]], 1);
}

// 3-phase parallel exclusive scan of deg[0..N_NODES)
__global__ __launch_bounds__(256) void k_scan_a(const int* __restrict__ deg,
                                                int* __restrict__ bsum) {
  __shared__ int s[256];
  int i = blockIdx.x * 256 + threadIdx.x;
  s[threadIdx.x] = (i < N_NODES) ? deg[i] : 0;
  __syncthreads();
  for (int off = 128; off > 0; off >>= 1) {
    if (threadIdx.x < off) s[threadIdx.x] += s[threadIdx.x + off];
    __syncthreads();
  }
  if (threadIdx.x == 0) bsum[blockIdx.x] = s[0];
}

__global__ __launch_bounds__(512) void k_scan_b(int* __restrict__ bsum) {
  __shared__ int s[512];
  const int t = threadIdx.x;
  int v = (t < NSB) ? bsum[t] : 0;
  s[t] = v;
  __syncthreads();
  for (int off = 1; off < 512; off <<= 1) {
    int w = (t >= off) ? s[t - off] : 0;
    __syncthreads();
    s[t] += w;
    __syncthreads();
  }
  if (t < NSB) bsum[t] = s[t] - v;   // exclusive block base
}

__global__ __launch_bounds__(256) void k_scan_c(const int* __restrict__ deg,
                                                const int* __restrict__ bsum,
                                                int* __restrict__ offs,
                                                float* __restrict__ invdeg) {
  __shared__ int s[256];
  const int t = threadIdx.x;
  const int i = blockIdx.x * 256 + t;
  const int d = (i < N_NODES) ? deg[i] : 0;
  s[t] = d;
  __syncthreads();
  for (int off = 1; off < 256; off <<= 1) {
    int w = (t >= off) ? s[t - off] : 0;
    __syncthreads();
    s[t] += w;
    __syncthreads();
  }
  if (i < N_NODES) {
    const int base = bsum[blockIdx.x];
    offs[i] = base + s[t] - d;
    invdeg[i] = 1.0f / (float)(d > 0 ? d : 1);
    if (i == N_NODES - 1) offs[N_NODES] = base + s[t];
  }
}

__global__ void k_fill(const int* __restrict__ src, const int* __restrict__ dst,
                       const int* __restrict__ offs, const int* __restrict__ epos,
                       int* __restrict__ csr) {
  int i = blockIdx.x * 256 + threadIdx.x;
  if (i < N_EDGES) csr[offs[dst[i]] + epos[i]] = src[i];
}

// ------------------------------------------------------------- bf16 MFMA GEMM
// C[M,N] = A[M,K] @ Bt[N,K]^T   (A,Bt bf16 row-major; C bf16 or f32)
// 128x128 tile, 4 waves (64x64 each = 4x4 frags of 16x16x32), BK=32,
// reg-staged LDS, next-tile register prefetch.
// bm from blockIdx.y, bn from blockIdx.x (x-consecutive blocks share A panel).
template <bool OUT_F32>
__global__ __launch_bounds__(256) void gemm_bt(const u16* __restrict__ A,
                                               const u16* __restrict__ Bt,
                                               void* __restrict__ Cv,
                                               int M, int N, int K) {
  __shared__ u16 As[128 * 32];
  __shared__ u16 Bs[128 * 32];
  const int tid  = threadIdx.x;
  const int lane = tid & 63;
  const int wid  = tid >> 6;
  const int wr   = wid >> 1, wc = wid & 1;
  const int bm0  = blockIdx.y * 128;
  const int bn0  = blockIdx.x * 128;

  const int sr = tid >> 2;          // staging row 0..63 (and +64)
  const int sc = (tid & 3) * 8;     // staging col (bf16 units)
  const long ar0 = (long)min(bm0 + sr,      M - 1) * K + sc;
  const long ar1 = (long)min(bm0 + sr + 64, M - 1) * K + sc;
  const long br0 = (long)(bn0 + sr)      * K + sc;
  const long br1 = (long)(bn0 + sr + 64) * K + sc;

  f32x4 acc[4][4];
#pragma unroll
  for (int i = 0; i < 4; ++i)
#pragma unroll
    for (int j = 0; j < 4; ++j) {
      f32x4 z = {0.f, 0.f, 0.f, 0.f};
      acc[i][j] = z;
    }

  uint4 a0 = *(const uint4*)(A + ar0);
  uint4 a1 = *(const uint4*)(A + ar1);
  uint4 b0 = *(const uint4*)(Bt + br0);
  uint4 b1 = *(const uint4*)(Bt + br1);

  const int nk = K >> 5;
  for (int kk = 0; kk < nk; ++kk) {
    *(uint4*)&As[sr * 32 + sc]        = a0;
    *(uint4*)&As[(sr + 64) * 32 + sc] = a1;
    *(uint4*)&Bs[sr * 32 + sc]        = b0;
    *(uint4*)&Bs[(sr + 64) * 32 + sc] = b1;
    __syncthreads();
    if (kk + 1 < nk) {
      const int k0 = (kk + 1) << 5;
      a0 = *(const uint4*)(A + ar0 + k0);
      a1 = *(const uint4*)(A + ar1 + k0);
      b0 = *(const uint4*)(Bt + br0 + k0);
      b1 = *(const uint4*)(Bt + br1 + k0);
    }
    bf16x8 af[4], bfr[4];
#pragma unroll
    for (int mi = 0; mi < 4; ++mi)
      af[mi] = *reinterpret_cast<const bf16x8*>(
          &As[(wr * 64 + mi * 16 + (lane & 15)) * 32 + ((lane >> 4) * 8)]);
#pragma unroll
    for (int ni = 0; ni < 4; ++ni)
      bfr[ni] = *reinterpret_cast<const bf16x8*>(
          &Bs[(wc * 64 + ni * 16 + (lane & 15)) * 32 + ((lane >> 4) * 8)]);
#pragma unroll
    for (int mi = 0; mi < 4; ++mi)
#pragma unroll
      for (int ni = 0; ni < 4; ++ni)
        acc[mi][ni] = __builtin_amdgcn_mfma_f32_16x16x32_bf16(
            af[mi], bfr[ni], acc[mi][ni], 0, 0, 0);
    __syncthreads();
  }

  // epilogue: C layout col = lane&15, row = (lane>>4)*4 + e   [m89-verified]
  const int colb = bn0 + wc * 64 + (lane & 15);
  const int rowb = bm0 + wr * 64 + ((lane >> 4) * 4);
#pragma unroll
  for (int mi = 0; mi < 4; ++mi) {
#pragma unroll
    for (int ni = 0; ni < 4; ++ni) {
      const int col = colb + ni * 16;
#pragma unroll
      for (int e = 0; e < 4; ++e) {
        const int row = rowb + mi * 16 + e;
        if (row < M) {
          if (OUT_F32)
            ((float*)Cv)[(long)row * N + col] = acc[mi][ni][e];
          else
            ((u16*)Cv)[(long)row * N + col] = f2bf(acc[mi][ni][e]);
        }
      }
    }
  }
}

// ------------------------------------------------------------- aggregation
// h1 = relu(z1_self + mean(z1_neigh) + b1) -> bf16 [N,256]; 4x unrolled gather
__global__ __launch_bounds__(256) void k_agg1(const u16* __restrict__ z1b,
                                              const int* __restrict__ csr,
                                              const int* __restrict__ offs,
                                              const float* __restrict__ invdeg,
                                              const float* __restrict__ b1,
                                              u16* __restrict__ h1b) {
  const int v = blockIdx.x;
  const int c = threadIdx.x;
  const int o0 = offs[v], o1 = offs[v + 1];
  float acc = 0.f;
  int i = o0;
  for (; i + 4 <= o1; i += 4) {
    const int u0 = csr[i], u1 = csr[i + 1], u2 = csr[i + 2], u3 = csr[i + 3];
    float p0 = bf2f(z1b[(long)u0 * 512 + 256 + c]);
    float p1 = bf2f(z1b[(long)u1 * 512 + 256 + c]);
    float p2 = bf2f(z1b[(long)u2 * 512 + 256 + c]);
    float p3 = bf2f(z1b[(long)u3 * 512 + 256 + c]);
    acc += (p0 + p1) + (p2 + p3);
  }
  for (; i < o1; ++i)
    acc += bf2f(z1b[(long)csr[i] * 512 + 256 + c]);
  float h = bf2f(z1b[(long)v * 512 + c]) + acc * invdeg[v] + b1[c];
  h1b[(long)v * 256 + c] = f2bf(fmaxf(h, 0.f));
}

// h2 = z2_self + mean(z2_neigh) + b2 -> bf16 [N,64]
__global__ __launch_bounds__(256) void k_agg2(const u16* __restrict__ z2b,
                                              const int* __restrict__ csr,
                                              const int* __restrict__ offs,
                                              const float* __restrict__ invdeg,
                                              const float* __restrict__ b2,
                                              u16* __restrict__ h2b) {
  const int v = blockIdx.x * 4 + (threadIdx.x >> 6);
  const int c = threadIdx.x & 63;
  const int o0 = offs[v], o1 = offs[v + 1];
  float acc = 0.f;
  int i = o0;
  for (; i + 4 <= o1; i += 4) {
    const int u0 = csr[i], u1 = csr[i + 1], u2 = csr[i + 2], u3 = csr[i + 3];
    float p0 = bf2f(z2b[(long)u0 * 128 + 64 + c]);
    float p1 = bf2f(z2b[(long)u1 * 128 + 64 + c]);
    float p2 = bf2f(z2b[(long)u2 * 128 + 64 + c]);
    float p3 = bf2f(z2b[(long)u3 * 128 + 64 + c]);
    acc += (p0 + p1) + (p2 + p3);
  }
  for (; i < o1; ++i)
    acc += bf2f(z2b[(long)csr[i] * 128 + 64 + c]);
  float h = bf2f(z2b[(long)v * 128 + c]) + acc * invdeg[v] + b2[c];
  h2b[(long)v * 64 + c] = f2bf(h);
}

// ------------------------------------------------------------- edge scoring
__global__ __launch_bounds__(256) void k_edge(const float* __restrict__ UV,
                                              const int* __restrict__ ps,
                                              const int* __restrict__ pd,
                                              const int* __restrict__ ns,
                                              const int* __restrict__ nd,
                                              const float* __restrict__ bp1,
                                              const float* __restrict__ Wp2,
                                              const float* __restrict__ bp2,
                                              float* __restrict__ out) {
  const int g = blockIdx.x * 4 + (threadIdx.x >> 6);   // edge id 0..399999
  const int j = threadIdx.x & 63;
  int s, d;
  if (g < EPOS) { s = ps[g]; d = pd[g]; }
  else          { s = ns[g - EPOS]; d = nd[g - EPOS]; }
  float t = UV[(long)s * 128 + j] + UV[(long)d * 128 + 64 + j] + bp1[j];
  float r = fmaxf(t, 0.f) * Wp2[j];
#pragma unroll
  for (int off = 32; off > 0; off >>= 1) r += __shfl_down(r, off, 64);
  if (j == 0) out[g] = r + bp2[0];
}

// ---------------------------------------------------------------- launcher
extern "C" void kernel_launch(void* const* d_in, const int* in_sizes, int n_in,
                              void* d_out, int out_size, void* d_ws, size_t ws_size,
                              hipStream_t stream) {
  const float* x   = (const float*)d_in[0];
  const int*   src = (const int*)d_in[1];
  const int*   dst = (const int*)d_in[2];
  const int*   ps  = (const int*)d_in[3];
  const int*   pd  = (const int*)d_in[4];
  const int*   ns  = (const int*)d_in[5];
  const int*   nd  = (const int*)d_in[6];
  const float* Ws1 = (const float*)d_in[7];
  const float* Wn1 = (const float*)d_in[8];
  const float* b1  = (const float*)d_in[9];
  const float* Ws2 = (const float*)d_in[10];
  const float* Wn2 = (const float*)d_in[11];
  const float* b2  = (const float*)d_in[12];
  const float* Wp1 = (const float*)d_in[13];
  const float* bp1 = (const float*)d_in[14];
  const float* Wp2 = (const float*)d_in[15];
  const float* bp2 = (const float*)d_in[16];
  float* out = (float*)d_out;

  // workspace layout (~211 MB), regions reused across phases:
  //  region A [0, 102.4MB):   xb (GEMM1 in) -> h1b (+0) , UV (+51.2MB)
  //  region B [102.4, 204.8): epos (CSR build) -> z1b -> z2b (+0), h2b (+25.6MB)
  //  region C [204.8, ~211):  W1t, W2t, Wpt, deg, offs, invdeg, bsum, csr
  char* ws = (char*)d_ws;
  const size_t RB = 102400000;
  const size_t RC = 204800000;
  u16*   xb  = (u16*)(ws);
  u16*   h1b = (u16*)(ws);                    // alias: xb dead after GEMM1
  float* UV  = (float*)(ws + 51200000);
  int*   epos= (int*)(ws + RB);               // dead after k_fill
  u16*   z1b = (u16*)(ws + RB);
  u16*   z2b = (u16*)(ws + RB);               // alias: z1b dead after agg1
  u16*   h2b = (u16*)(ws + RB + 25600000);
  size_t o = RC;
  u16*   W1t = (u16*)(ws + o); o += 524288;
  u16*   W2t = (u16*)(ws + o); o += 65536;
  u16*   Wpt = (u16*)(ws + o); o += 16384;
  int*   deg = (int*)(ws + o); o += 400128;
  int*   offs= (int*)(ws + o); o += 400128;
  float* idg = (float*)(ws + o); o += 400128;
  int*   bsum= (int*)(ws + o); o += 2048;
  int*   csr = (int*)(ws + o); o += 4000000;
  (void)ws_size; (void)in_sizes; (void)n_in; (void)out_size;

  hipMemsetAsync(deg, 0, 400128, stream);

  k_x2bf<<<25000, 256, 0, stream>>>(x, xb);
  k_w1t<<<1024, 256, 0, stream>>>(Ws1, Wn1, W1t);
  k_w2t<<<128, 256, 0, stream>>>(Ws2, Wn2, W2t);
  k_wpt<<<32, 256, 0, stream>>>(Wp1, Wpt);
  k_deg<<<3907, 256, 0, stream>>>(dst, deg, epos);
  k_scan_a<<<NSB, 256, 0, stream>>>(deg, bsum);
  k_scan_b<<<1, 512, 0, stream>>>(bsum);
  k_scan_c<<<NSB, 256, 0, stream>>>(deg, bsum, offs, idg);
  k_fill<<<3907, 256, 0, stream>>>(src, dst, offs, epos, csr);

  gemm_bt<false><<<dim3(4, 782), 256, 0, stream>>>(xb, W1t, z1b, N_NODES, 512, 512);
  k_agg1<<<100000, 256, 0, stream>>>(z1b, csr, offs, idg, b1, h1b);
  gemm_bt<false><<<dim3(1, 782), 256, 0, stream>>>(h1b, W2t, z2b, N_NODES, 128, 256);
  k_agg2<<<25000, 256, 0, stream>>>(z2b, csr, offs, idg, b2, h2b);
  gemm_bt<true><<<dim3(1, 782), 256, 0, stream>>>(h2b, Wpt, UV, N_NODES, 128, 64);
  k_edge<<<100000, 256, 0, stream>>>(UV, ps, pd, ns, nd, bp1, Wp2, bp2, out);
}

// Round 3
// 740.229 us; speedup vs baseline: 1.5480x; 1.0463x over previous
//
#include <hip/hip_runtime.h>
#include <hip/hip_bf16.h>

// DoubleSAGE link predictor, restructured:
//   z1 = x @ [W_self1 | W_neigh1]          (bf16 MFMA GEMM, N=512)
//   h1 = relu(z1_self + CSR-mean(z1_neigh) + b1)
//   z2 = h1 @ [W_self2 | W_neigh2]         (N=128)
//   h2 = z2_self + CSR-mean(z2_neigh) + b2
//   UV = h2 @ [Wp1_top | Wp1_bot]          (N=128, bf16 out)
//   score(s,d) = relu(UV[s][:64] + UV[d][64:] + bp1) . Wp2 + bp2
// CSR built per-call: atomic histogram (records slot) + 3-phase parallel
// scan + non-atomic fill. GEMM: 128x128 tile, global_load_lds dbuf 2-phase.

#define N_NODES 100000
#define N_EDGES 1000000
#define EPOS    200000
#define NSB     391        // ceil(N_NODES/256) scan blocks

typedef unsigned short u16;
typedef unsigned int   u32;

typedef __bf16 bf16x8 __attribute__((ext_vector_type(8)));
typedef float  f32x4  __attribute__((ext_vector_type(4)));
typedef u16    u16x8  __attribute__((ext_vector_type(8)));

__device__ __forceinline__ u16 f2bf(float f) {
  u32 u = __float_as_uint(f);
  u32 r = (u + 0x7fffu + ((u >> 16) & 1u)) >> 16;   // RNE
  return (u16)r;
}
__device__ __forceinline__ float bf2f(u16 h) {
  return __uint_as_float(((u32)h) << 16);
}

__device__ __forceinline__ void gl_lds16(const void* g, void* l) {
  __builtin_amdgcn_global_load_lds(
      (const __attribute__((address_space(1))) void*)g,
      (__attribute__((address_space(3))) void*)l, 16, 0, 0);
}

// ---------------------------------------------------------------- convert x
__global__ __launch_bounds__(256) void k_x2bf(const float* __restrict__ in,
                                              u16* __restrict__ out) {
  long i = ((long)blockIdx.x * 256 + threadIdx.x) * 8;
  float4 f0 = *(const float4*)(in + i);
  float4 f1 = *(const float4*)(in + i + 4);
  u16x8 o;
  o[0] = f2bf(f0.x); o[1] = f2bf(f0.y); o[2] = f2bf(f0.z); o[3] = f2bf(f0.w);
  o[4] = f2bf(f1.x); o[5] = f2bf(f1.y); o[6] = f2bf(f1.z); o[7] = f2bf(f1.w);
  *(u16x8*)(out + i) = o;
}

// ------------------------------------------------------- weight repack (B^T)
__global__ void k_w1t(const float* __restrict__ Ws, const float* __restrict__ Wn,
                      u16* __restrict__ W1t) {
  int idx = blockIdx.x * 256 + threadIdx.x;   // < 512*512
  int j = idx >> 9, k = idx & 511;
  float v = (j < 256) ? Ws[k * 256 + j] : Wn[k * 256 + (j - 256)];
  W1t[idx] = f2bf(v);
}
__global__ void k_w2t(const float* __restrict__ Ws, const float* __restrict__ Wn,
                      u16* __restrict__ W2t) {
  int idx = blockIdx.x * 256 + threadIdx.x;   // < 128*256
  int j = idx >> 8, k = idx & 255;
  float v = (j < 64) ? Ws[k * 64 + j] : Wn[k * 64 + (j - 64)];
  W2t[idx] = f2bf(v);
}
__global__ void k_wpt(const float* __restrict__ Wp1, u16* __restrict__ Wpt) {
  int idx = blockIdx.x * 256 + threadIdx.x;   // < 128*64
  int j = idx >> 6, k = idx & 63;
  float v = (j < 64) ? Wp1[k * 64 + j] : Wp1[(64 + k) * 64 + (j - 64)];
  Wpt[idx] = f2bf(v);
}

// ---------------------------------------------------------------- CSR build
__global__ void k_deg(const int* __restrict__ dst, int* __restrict__ deg,
                      int* __restrict__ epos) {
  int i = blockIdx.x * 256 + threadIdx.x;
  if (i < N_EDGES) epos[i] = atomicAdd(&deg[dst[i]], 1);
}

__global__ __launch_bounds__(256) void k_scan_a(const int* __restrict__ deg,
                                                int* __restrict__ bsum) {
  __shared__ int s[256];
  int i = blockIdx.x * 256 + threadIdx.x;
  s[threadIdx.x] = (i < N_NODES) ? deg[i] : 0;
  __syncthreads();
  for (int off = 128; off > 0; off >>= 1) {
    if (threadIdx.x < off) s[threadIdx.x] += s[threadIdx.x + off];
    __syncthreads();
  }
  if (threadIdx.x == 0) bsum[blockIdx.x] = s[0];
}

__global__ __launch_bounds__(512) void k_scan_b(int* __restrict__ bsum) {
  __shared__ int s[512];
  const int t = threadIdx.x;
  int v = (t < NSB) ? bsum[t] : 0;
  s[t] = v;
  __syncthreads();
  for (int off = 1; off < 512; off <<= 1) {
    int w = (t >= off) ? s[t - off] : 0;
    __syncthreads();
    s[t] += w;
    __syncthreads();
  }
  if (t < NSB) bsum[t] = s[t] - v;   // exclusive block base
}

__global__ __launch_bounds__(256) void k_scan_c(const int* __restrict__ deg,
                                                const int* __restrict__ bsum,
                                                int* __restrict__ offs,
                                                float* __restrict__ invdeg) {
  __shared__ int s[256];
  const int t = threadIdx.x;
  const int i = blockIdx.x * 256 + t;
  const int d = (i < N_NODES) ? deg[i] : 0;
  s[t] = d;
  __syncthreads();
  for (int off = 1; off < 256; off <<= 1) {
    int w = (t >= off) ? s[t - off] : 0;
    __syncthreads();
    s[t] += w;
    __syncthreads();
  }
  if (i < N_NODES) {
    const int base = bsum[blockIdx.x];
    offs[i] = base + s[t] - d;
    invdeg[i] = 1.0f / (float)(d > 0 ? d : 1);
    if (i == N_NODES - 1) offs[N_NODES] = base + s[t];
  }
}

__global__ void k_fill(const int* __restrict__ src, const int* __restrict__ dst,
                       const int* __restrict__ offs, const int* __restrict__ epos,
                       int* __restrict__ csr) {
  int i = blockIdx.x * 256 + threadIdx.x;
  if (i < N_EDGES) csr[offs[dst[i]] + epos[i]] = src[i];
}

// ------------------------------------------------------------- bf16 MFMA GEMM
// C[M,N] = A[M,K] @ Bt[N,K]^T.  128x128 tile, 4 waves (64x64 each),
// BK=32, double-buffered LDS filled by global_load_lds dwordx4,
// T3 minimum-2-phase schedule (stage next || compute cur, 1 barrier/tile).
template <bool OUT_F32>
__global__ __launch_bounds__(256) void gemm_bt(const u16* __restrict__ A,
                                               const u16* __restrict__ Bt,
                                               void* __restrict__ Cv,
                                               int M, int N, int K) {
  __shared__ u16 As[2][4096];
  __shared__ u16 Bs[2][4096];
  const int tid  = threadIdx.x;
  const int lane = tid & 63;
  const int wid  = tid >> 6;
  const int wr   = wid >> 1, wc = wid & 1;
  const int bm0  = blockIdx.y * 128;
  const int bn0  = blockIdx.x * 128;

  const int sr = tid >> 2;          // staging row 0..63 (and +64)
  const int sc = (tid & 3) * 8;     // staging col (bf16 units)
  const u16* pa0 = A  + (long)min(bm0 + sr,      M - 1) * K + sc;
  const u16* pa1 = A  + (long)min(bm0 + sr + 64, M - 1) * K + sc;
  const u16* pb0 = Bt + (long)(bn0 + sr)      * K + sc;
  const u16* pb1 = Bt + (long)(bn0 + sr + 64) * K + sc;
  const int lw = wid * 512;         // wave-uniform LDS base (u16 units)

  f32x4 acc[4][4];
#pragma unroll
  for (int i = 0; i < 4; ++i)
#pragma unroll
    for (int j = 0; j < 4; ++j) {
      f32x4 z = {0.f, 0.f, 0.f, 0.f};
      acc[i][j] = z;
    }

  const int nk = K >> 5;
#define STAGE(buf, kk) do { const int k0_ = (kk) << 5;                    \
    gl_lds16(pa0 + k0_, &As[buf][lw]);                                    \
    gl_lds16(pa1 + k0_, &As[buf][2048 + lw]);                             \
    gl_lds16(pb0 + k0_, &Bs[buf][lw]);                                    \
    gl_lds16(pb1 + k0_, &Bs[buf][2048 + lw]); } while (0)

  STAGE(0, 0);
  __syncthreads();
  int cur = 0;
  for (int kk = 0; kk < nk; ++kk) {
    if (kk + 1 < nk) STAGE(cur ^ 1, kk + 1);   // async, flies over compute
    bf16x8 af[4], bfr[4];
#pragma unroll
    for (int mi = 0; mi < 4; ++mi)
      af[mi] = *reinterpret_cast<const bf16x8*>(
          &As[cur][(wr * 64 + mi * 16 + (lane & 15)) * 32 + ((lane >> 4) * 8)]);
#pragma unroll
    for (int ni = 0; ni < 4; ++ni)
      bfr[ni] = *reinterpret_cast<const bf16x8*>(
          &Bs[cur][(wc * 64 + ni * 16 + (lane & 15)) * 32 + ((lane >> 4) * 8)]);
#pragma unroll
    for (int mi = 0; mi < 4; ++mi)
#pragma unroll
      for (int ni = 0; ni < 4; ++ni)
        acc[mi][ni] = __builtin_amdgcn_mfma_f32_16x16x32_bf16(
            af[mi], bfr[ni], acc[mi][ni], 0, 0, 0);
    __syncthreads();   // drains vmcnt(0)+lgkmcnt(0): next buf ready, cur free
    cur ^= 1;
  }
#undef STAGE

  // epilogue: C layout col = lane&15, row = (lane>>4)*4 + e   [m89-verified]
  const int colb = bn0 + wc * 64 + (lane & 15);
  const int rowb = bm0 + wr * 64 + ((lane >> 4) * 4);
#pragma unroll
  for (int mi = 0; mi < 4; ++mi) {
#pragma unroll
    for (int ni = 0; ni < 4; ++ni) {
      const int col = colb + ni * 16;
#pragma unroll
      for (int e = 0; e < 4; ++e) {
        const int row = rowb + mi * 16 + e;
        if (row < M) {
          if (OUT_F32)
            ((float*)Cv)[(long)row * N + col] = acc[mi][ni][e];
          else
            ((u16*)Cv)[(long)row * N + col] = f2bf(acc[mi][ni][e]);
        }
      }
    }
  }
}

// ------------------------------------------------------------- aggregation
// h1 = relu(z1_self + mean(z1_neigh) + b1) -> bf16 [N,256]
// one node per 64-lane wave; lane owns 4 channels (ushort4 = 8 B loads);
// 4-edge unroll = 4x8B in flight per lane; 4 nodes/block.
__global__ __launch_bounds__(256) void k_agg1(const u16* __restrict__ z1b,
                                              const int* __restrict__ csr,
                                              const int* __restrict__ offs,
                                              const float* __restrict__ invdeg,
                                              const float* __restrict__ b1,
                                              u16* __restrict__ h1b) {
  const int v    = blockIdx.x * 4 + (threadIdx.x >> 6);
  const int lane = threadIdx.x & 63;
  const int c    = lane * 4;                  // channel base
  const int o0 = offs[v], o1 = offs[v + 1];
  float a0 = 0.f, a1 = 0.f, a2 = 0.f, a3 = 0.f;
  int i = o0;
  for (; i + 4 <= o1; i += 4) {
    const int u0 = csr[i], u1 = csr[i + 1], u2 = csr[i + 2], u3 = csr[i + 3];
    ushort4 q0 = *(const ushort4*)&z1b[(long)u0 * 512 + 256 + c];
    ushort4 q1 = *(const ushort4*)&z1b[(long)u1 * 512 + 256 + c];
    ushort4 q2 = *(const ushort4*)&z1b[(long)u2 * 512 + 256 + c];
    ushort4 q3 = *(const ushort4*)&z1b[(long)u3 * 512 + 256 + c];
    a0 += (bf2f(q0.x) + bf2f(q1.x)) + (bf2f(q2.x) + bf2f(q3.x));
    a1 += (bf2f(q0.y) + bf2f(q1.y)) + (bf2f(q2.y) + bf2f(q3.y));
    a2 += (bf2f(q0.z) + bf2f(q1.z)) + (bf2f(q2.z) + bf2f(q3.z));
    a3 += (bf2f(q0.w) + bf2f(q1.w)) + (bf2f(q2.w) + bf2f(q3.w));
  }
  for (; i < o1; ++i) {
    ushort4 q = *(const ushort4*)&z1b[(long)csr[i] * 512 + 256 + c];
    a0 += bf2f(q.x); a1 += bf2f(q.y); a2 += bf2f(q.z); a3 += bf2f(q.w);
  }
  const float w = invdeg[v];
  ushort4 sf = *(const ushort4*)&z1b[(long)v * 512 + c];
  float4 bb = *(const float4*)&b1[c];
  ushort4 o;
  o.x = f2bf(fmaxf(bf2f(sf.x) + a0 * w + bb.x, 0.f));
  o.y = f2bf(fmaxf(bf2f(sf.y) + a1 * w + bb.y, 0.f));
  o.z = f2bf(fmaxf(bf2f(sf.z) + a2 * w + bb.z, 0.f));
  o.w = f2bf(fmaxf(bf2f(sf.w) + a3 * w + bb.w, 0.f));
  *(ushort4*)&h1b[(long)v * 256 + c] = o;
}

// h2 = z2_self + mean(z2_neigh) + b2 -> bf16 [N,64]
// one node per wave; half-wave = even edges, half-wave = odd edges;
// lane owns 2 channels (u32 loads); shfl_xor(32) merges the halves.
__global__ __launch_bounds__(256) void k_agg2(const u16* __restrict__ z2b,
                                              const int* __restrict__ csr,
                                              const int* __restrict__ offs,
                                              const float* __restrict__ invdeg,
                                              const float* __restrict__ b2,
                                              u16* __restrict__ h2b) {
  const int v    = blockIdx.x * 4 + (threadIdx.x >> 6);
  const int lane = threadIdx.x & 63;
  const int half = lane >> 5;
  const int c    = (lane & 31) * 2;
  const int o0 = offs[v], o1 = offs[v + 1];
  float a0 = 0.f, a1 = 0.f;
  for (int i = o0 + half; i < o1; i += 2) {
    const u32 q = *(const u32*)&z2b[(long)csr[i] * 128 + 64 + c];
    a0 += bf2f((u16)q);
    a1 += bf2f((u16)(q >> 16));
  }
  a0 += __shfl_xor(a0, 32);
  a1 += __shfl_xor(a1, 32);
  if (half == 0) {
    const float w = invdeg[v];
    const u32 sq = *(const u32*)&z2b[(long)v * 128 + c];
    float h0 = bf2f((u16)sq) + a0 * w + b2[c];
    float h1 = bf2f((u16)(sq >> 16)) + a1 * w + b2[c + 1];
    u32 o = (u32)f2bf(h0) | ((u32)f2bf(h1) << 16);
    *(u32*)&h2b[(long)v * 64 + c] = o;
  }
}

// ------------------------------------------------------------- edge scoring
// UV stored bf16 [N,128]. One edge per wave: lanes 0-31 load U[s] (2ch/lane),
// lanes 32-63 load V[d]; shfl_xor(32) combines; 32-lane tree reduce.
__global__ __launch_bounds__(256) void k_edge(const u16* __restrict__ UVb,
                                              const int* __restrict__ ps,
                                              const int* __restrict__ pd,
                                              const int* __restrict__ ns,
                                              const int* __restrict__ nd,
                                              const float* __restrict__ bp1,
                                              const float* __restrict__ Wp2,
                                              const float* __restrict__ bp2,
                                              float* __restrict__ out) {
  const int g    = blockIdx.x * 4 + (threadIdx.x >> 6);   // edge id
  const int lane = threadIdx.x & 63;
  const int half = lane >> 5;
  const int l    = lane & 31;
  int s, d;
  if (g < EPOS) { s = ps[g]; d = pd[g]; }
  else          { s = ns[g - EPOS]; d = nd[g - EPOS]; }
  const int node = half ? d : s;
  const u32 q = *(const u32*)&UVb[(long)node * 128 + half * 64 + 2 * l];
  float t0 = bf2f((u16)q), t1 = bf2f((u16)(q >> 16));
  t0 += __shfl_xor(t0, 32);
  t1 += __shfl_xor(t1, 32);
  const float2 bb = *(const float2*)&bp1[2 * l];
  const float2 ww = *(const float2*)&Wp2[2 * l];
  float p = fmaxf(t0 + bb.x, 0.f) * ww.x + fmaxf(t1 + bb.y, 0.f) * ww.y;
#pragma unroll
  for (int off = 16; off > 0; off >>= 1) p += __shfl_xor(p, off);
  if (lane == 0) out[g] = p + bp2[0];
}

// ---------------------------------------------------------------- launcher
extern "C" void kernel_launch(void* const* d_in, const int* in_sizes, int n_in,
                              void* d_out, int out_size, void* d_ws, size_t ws_size,
                              hipStream_t stream) {
  const float* x   = (const float*)d_in[0];
  const int*   src = (const int*)d_in[1];
  const int*   dst = (const int*)d_in[2];
  const int*   ps  = (const int*)d_in[3];
  const int*   pd  = (const int*)d_in[4];
  const int*   ns  = (const int*)d_in[5];
  const int*   nd  = (const int*)d_in[6];
  const float* Ws1 = (const float*)d_in[7];
  const float* Wn1 = (const float*)d_in[8];
  const float* b1  = (const float*)d_in[9];
  const float* Ws2 = (const float*)d_in[10];
  const float* Wn2 = (const float*)d_in[11];
  const float* b2  = (const float*)d_in[12];
  const float* Wp1 = (const float*)d_in[13];
  const float* bp1 = (const float*)d_in[14];
  const float* Wp2 = (const float*)d_in[15];
  const float* bp2 = (const float*)d_in[16];
  float* out = (float*)d_out;

  // workspace layout (~211 MB), regions reused across phases:
  //  region A [0, 102.4MB):   xb (GEMM1 in) -> h1b (+0), UVb (+51.2MB, bf16)
  //  region B [102.4, 204.8): epos (CSR build) -> z1b -> z2b (+0), h2b (+25.6MB)
  //  region C [204.8, ~211):  W1t, W2t, Wpt, deg, offs, invdeg, bsum, csr
  char* ws = (char*)d_ws;
  const size_t RB = 102400000;
  const size_t RC = 204800000;
  u16*   xb  = (u16*)(ws);
  u16*   h1b = (u16*)(ws);                    // alias: xb dead after GEMM1
  u16*   UVb = (u16*)(ws + 51200000);
  int*   epos= (int*)(ws + RB);               // dead after k_fill
  u16*   z1b = (u16*)(ws + RB);
  u16*   z2b = (u16*)(ws + RB);               // alias: z1b dead after agg1
  u16*   h2b = (u16*)(ws + RB + 25600000);
  size_t o = RC;
  u16*   W1t = (u16*)(ws + o); o += 524288;
  u16*   W2t = (u16*)(ws + o); o += 65536;
  u16*   Wpt = (u16*)(ws + o); o += 16384;
  int*   deg = (int*)(ws + o); o += 400128;
  int*   offs= (int*)(ws + o); o += 400128;
  float* idg = (float*)(ws + o); o += 400128;
  int*   bsum= (int*)(ws + o); o += 2048;
  int*   csr = (int*)(ws + o); o += 4000000;
  (void)ws_size; (void)in_sizes; (void)n_in; (void)out_size;

  hipMemsetAsync(deg, 0, 400128, stream);

  k_x2bf<<<25000, 256, 0, stream>>>(x, xb);
  k_w1t<<<1024, 256, 0, stream>>>(Ws1, Wn1, W1t);
  k_w2t<<<128, 256, 0, stream>>>(Ws2, Wn2, W2t);
  k_wpt<<<32, 256, 0, stream>>>(Wp1, Wpt);
  k_deg<<<3907, 256, 0, stream>>>(dst, deg, epos);
  k_scan_a<<<NSB, 256, 0, stream>>>(deg, bsum);
  k_scan_b<<<1, 512, 0, stream>>>(bsum);
  k_scan_c<<<NSB, 256, 0, stream>>>(deg, bsum, offs, idg);
  k_fill<<<3907, 256, 0, stream>>>(src, dst, offs, epos, csr);

  gemm_bt<false><<<dim3(4, 782), 256, 0, stream>>>(xb, W1t, z1b, N_NODES, 512, 512);
  k_agg1<<<25000, 256, 0, stream>>>(z1b, csr, offs, idg, b1, h1b);
  gemm_bt<false><<<dim3(1, 782), 256, 0, stream>>>(h1b, W2t, z2b, N_NODES, 128, 256);
  k_agg2<<<25000, 256, 0, stream>>>(z2b, csr, offs, idg, b2, h2b);
  gemm_bt<false><<<dim3(1, 782), 256, 0, stream>>>(h2b, Wpt, UVb, N_NODES, 128, 64);
  k_edge<<<100000, 256, 0, stream>>>(UVb, ps, pd, ns, nd, bp1, Wp2, bp2, out);
}

// Round 4
// 715.978 us; speedup vs baseline: 1.6005x; 1.0339x over previous
//
#include <hip/hip_runtime.h>
#include <hip/hip_bf16.h>

// DoubleSAGE link predictor, restructured:
//   z1 = x @ [W_self1 | W_neigh1]          (bf16 MFMA GEMM, N=512)
//   h1 = relu(z1_self + CSR-mean(z1_neigh) + b1)
//   z2 = h1 @ [W_self2 | W_neigh2]         (N=128)
//   h2 = z2_self + CSR-mean(z2_neigh) + b2
//   UV = h2 @ [Wp1_top | Wp1_bot]          (N=128, bf16 out)
//   score(s,d) = relu(UV[s][:64] + UV[d][64:] + bp1) . Wp2 + bp2
// CSR built per-call (atomic histogram + 3-phase scan + non-atomic fill).
// GEMM: 128x128 tile, global_load_lds dbuf 2-phase; GEMM1 uses bijective
// XCD-chunked swizzle (3128 = 8*391) so each A-panel's 4 bn-blocks land
// consecutively on one XCD -> panel read once from HBM, 3x L2 hits.

#define N_NODES 100000
#define N_EDGES 1000000
#define EPOS    200000
#define NSB     391        // ceil(N_NODES/256) scan blocks

typedef unsigned short u16;
typedef unsigned int   u32;

typedef __bf16 bf16x8 __attribute__((ext_vector_type(8)));
typedef float  f32x4  __attribute__((ext_vector_type(4)));
typedef u16    u16x8  __attribute__((ext_vector_type(8)));

__device__ __forceinline__ u16 f2bf(float f) {
  u32 u = __float_as_uint(f);
  u32 r = (u + 0x7fffu + ((u >> 16) & 1u)) >> 16;   // RNE
  return (u16)r;
}
__device__ __forceinline__ float bf2f(u16 h) {
  return __uint_as_float(((u32)h) << 16);
}

__device__ __forceinline__ void gl_lds16(const void* g, void* l) {
  __builtin_amdgcn_global_load_lds(
      (const __attribute__((address_space(1))) void*)g,
      (__attribute__((address_space(3))) void*)l, 16, 0, 0);
}

// ------------------------------------------------- fused prep (1 dispatch)
// blocks [0,25000): x f32 -> bf16          (8 elem/thread)
// [25000,28907):   deg histogram + epos    (1 edge/thread)
// [28907,29931):   W1t repack              (512x512)
// [29931,30059):   W2t repack              (128x256)
// [30059,30091):   Wpt repack              (128x64)
__global__ __launch_bounds__(256) void k_prep(
    const float* __restrict__ x, u16* __restrict__ xb,
    const int* __restrict__ dst, int* __restrict__ deg, int* __restrict__ epos,
    const float* __restrict__ Ws1, const float* __restrict__ Wn1, u16* __restrict__ W1t,
    const float* __restrict__ Ws2, const float* __restrict__ Wn2, u16* __restrict__ W2t,
    const float* __restrict__ Wp1, u16* __restrict__ Wpt) {
  const int bid = blockIdx.x;
  const int tid = threadIdx.x;
  if (bid < 25000) {
    long i = ((long)bid * 256 + tid) * 8;
    float4 f0 = *(const float4*)(x + i);
    float4 f1 = *(const float4*)(x + i + 4);
    u16x8 o;
    o[0] = f2bf(f0.x); o[1] = f2bf(f0.y); o[2] = f2bf(f0.z); o[3] = f2bf(f0.w);
    o[4] = f2bf(f1.x); o[5] = f2bf(f1.y); o[6] = f2bf(f1.z); o[7] = f2bf(f1.w);
    *(u16x8*)(xb + i) = o;
  } else if (bid < 28907) {
    int e = (bid - 25000) * 256 + tid;
    if (e < N_EDGES) epos[e] = atomicAdd(&deg[dst[e]], 1);
  } else if (bid < 29931) {
    int idx = (bid - 28907) * 256 + tid;      // < 512*512
    int j = idx >> 9, k = idx & 511;
    float v = (j < 256) ? Ws1[k * 256 + j] : Wn1[k * 256 + (j - 256)];
    W1t[idx] = f2bf(v);
  } else if (bid < 30059) {
    int idx = (bid - 29931) * 256 + tid;      // < 128*256
    int j = idx >> 8, k = idx & 255;
    float v = (j < 64) ? Ws2[k * 64 + j] : Wn2[k * 64 + (j - 64)];
    W2t[idx] = f2bf(v);
  } else {
    int idx = (bid - 30059) * 256 + tid;      // < 128*64
    int j = idx >> 6, k = idx & 63;
    float v = (j < 64) ? Wp1[k * 64 + j] : Wp1[(64 + k) * 64 + (j - 64)];
    Wpt[idx] = f2bf(v);
  }
}

// ---------------------------------------------------------------- CSR scan
__global__ __launch_bounds__(256) void k_scan_a(const int* __restrict__ deg,
                                                int* __restrict__ bsum) {
  __shared__ int s[256];
  int i = blockIdx.x * 256 + threadIdx.x;
  s[threadIdx.x] = (i < N_NODES) ? deg[i] : 0;
  __syncthreads();
  for (int off = 128; off > 0; off >>= 1) {
    if (threadIdx.x < off) s[threadIdx.x] += s[threadIdx.x + off];
    __syncthreads();
  }
  if (threadIdx.x == 0) bsum[blockIdx.x] = s[0];
}

__global__ __launch_bounds__(512) void k_scan_b(int* __restrict__ bsum) {
  __shared__ int s[512];
  const int t = threadIdx.x;
  int v = (t < NSB) ? bsum[t] : 0;
  s[t] = v;
  __syncthreads();
  for (int off = 1; off < 512; off <<= 1) {
    int w = (t >= off) ? s[t - off] : 0;
    __syncthreads();
    s[t] += w;
    __syncthreads();
  }
  if (t < NSB) bsum[t] = s[t] - v;   // exclusive block base
}

__global__ __launch_bounds__(256) void k_scan_c(const int* __restrict__ deg,
                                                const int* __restrict__ bsum,
                                                int* __restrict__ offs,
                                                float* __restrict__ invdeg) {
  __shared__ int s[256];
  const int t = threadIdx.x;
  const int i = blockIdx.x * 256 + t;
  const int d = (i < N_NODES) ? deg[i] : 0;
  s[t] = d;
  __syncthreads();
  for (int off = 1; off < 256; off <<= 1) {
    int w = (t >= off) ? s[t - off] : 0;
    __syncthreads();
    s[t] += w;
    __syncthreads();
  }
  if (i < N_NODES) {
    const int base = bsum[blockIdx.x];
    offs[i] = base + s[t] - d;
    invdeg[i] = 1.0f / (float)(d > 0 ? d : 1);
    if (i == N_NODES - 1) offs[N_NODES] = base + s[t];
  }
}

__global__ void k_fill(const int* __restrict__ src, const int* __restrict__ dst,
                       const int* __restrict__ offs, const int* __restrict__ epos,
                       int* __restrict__ csr) {
  int i = blockIdx.x * 256 + threadIdx.x;
  if (i < N_EDGES) csr[offs[dst[i]] + epos[i]] = src[i];
}

// ------------------------------------------------------------- bf16 MFMA GEMM
// C[M,N] = A[M,K] @ Bt[N,K]^T.  128x128 tile, 4 waves (64x64 each),
// BK=32, double-buffered LDS filled by global_load_lds dwordx4,
// 2-phase schedule (stage next || compute cur, 1 barrier/tile).
// SWZ1: 1-D grid of 3128 blocks, bijective XCD-chunked (bm,bn) mapping.
template <bool OUT_F32, bool SWZ1>
__global__ __launch_bounds__(256) void gemm_bt(const u16* __restrict__ A,
                                               const u16* __restrict__ Bt,
                                               void* __restrict__ Cv,
                                               int M, int N, int K) {
  __shared__ u16 As[2][4096];
  __shared__ u16 Bs[2][4096];
  const int tid  = threadIdx.x;
  const int lane = tid & 63;
  const int wid  = tid >> 6;
  const int wr   = wid >> 1, wc = wid & 1;
  int bm0, bn0;
  if (SWZ1) {
    const int d = blockIdx.x;                 // 3128 = 8 * 391
    const int s = (d & 7) * 391 + (d >> 3);   // XCD-chunked, bijective
    bm0 = (s >> 2) * 128;
    bn0 = (s & 3) * 128;
  } else {
    bm0 = blockIdx.y * 128;
    bn0 = blockIdx.x * 128;
  }

  const int sr = tid >> 2;          // staging row 0..63 (and +64)
  const int sc = (tid & 3) * 8;     // staging col (bf16 units)
  const u16* pa0 = A  + (long)min(bm0 + sr,      M - 1) * K + sc;
  const u16* pa1 = A  + (long)min(bm0 + sr + 64, M - 1) * K + sc;
  const u16* pb0 = Bt + (long)(bn0 + sr)      * K + sc;
  const u16* pb1 = Bt + (long)(bn0 + sr + 64) * K + sc;
  const int lw = wid * 512;         // wave-uniform LDS base (u16 units)

  f32x4 acc[4][4];
#pragma unroll
  for (int i = 0; i < 4; ++i)
#pragma unroll
    for (int j = 0; j < 4; ++j) {
      f32x4 z = {0.f, 0.f, 0.f, 0.f};
      acc[i][j] = z;
    }

  const int nk = K >> 5;
#define STAGE(buf, kk) do { const int k0_ = (kk) << 5;                    \
    gl_lds16(pa0 + k0_, &As[buf][lw]);                                    \
    gl_lds16(pa1 + k0_, &As[buf][2048 + lw]);                             \
    gl_lds16(pb0 + k0_, &Bs[buf][lw]);                                    \
    gl_lds16(pb1 + k0_, &Bs[buf][2048 + lw]); } while (0)

  STAGE(0, 0);
  __syncthreads();
  int cur = 0;
  for (int kk = 0; kk < nk; ++kk) {
    if (kk + 1 < nk) STAGE(cur ^ 1, kk + 1);   // async, flies over compute
    bf16x8 af[4], bfr[4];
#pragma unroll
    for (int mi = 0; mi < 4; ++mi)
      af[mi] = *reinterpret_cast<const bf16x8*>(
          &As[cur][(wr * 64 + mi * 16 + (lane & 15)) * 32 + ((lane >> 4) * 8)]);
#pragma unroll
    for (int ni = 0; ni < 4; ++ni)
      bfr[ni] = *reinterpret_cast<const bf16x8*>(
          &Bs[cur][(wc * 64 + ni * 16 + (lane & 15)) * 32 + ((lane >> 4) * 8)]);
#pragma unroll
    for (int mi = 0; mi < 4; ++mi)
#pragma unroll
      for (int ni = 0; ni < 4; ++ni)
        acc[mi][ni] = __builtin_amdgcn_mfma_f32_16x16x32_bf16(
            af[mi], bfr[ni], acc[mi][ni], 0, 0, 0);
    __syncthreads();   // drains vmcnt(0)+lgkmcnt(0): next buf ready, cur free
    cur ^= 1;
  }
#undef STAGE

  // epilogue: C layout col = lane&15, row = (lane>>4)*4 + e   [m89-verified]
  const int colb = bn0 + wc * 64 + (lane & 15);
  const int rowb = bm0 + wr * 64 + ((lane >> 4) * 4);
#pragma unroll
  for (int mi = 0; mi < 4; ++mi) {
#pragma unroll
    for (int ni = 0; ni < 4; ++ni) {
      const int col = colb + ni * 16;
#pragma unroll
      for (int e = 0; e < 4; ++e) {
        const int row = rowb + mi * 16 + e;
        if (row < M) {
          if (OUT_F32)
            ((float*)Cv)[(long)row * N + col] = acc[mi][ni][e];
          else
            ((u16*)Cv)[(long)row * N + col] = f2bf(acc[mi][ni][e]);
        }
      }
    }
  }
}

// ------------------------------------------------------------- aggregation
// h1 = relu(z1_self + mean(z1_neigh) + b1) -> bf16 [N,256]
// one node per 64-lane wave; lane owns 4 channels (ushort4 = 8 B loads);
// 8/4/1 unroll ladder = up to 8x8B in flight per lane; 4 nodes/block.
__global__ __launch_bounds__(256) void k_agg1(const u16* __restrict__ z1b,
                                              const int* __restrict__ csr,
                                              const int* __restrict__ offs,
                                              const float* __restrict__ invdeg,
                                              const float* __restrict__ b1,
                                              u16* __restrict__ h1b) {
  const int v    = blockIdx.x * 4 + (threadIdx.x >> 6);
  const int lane = threadIdx.x & 63;
  const int c    = lane * 4;                  // channel base
  const int o0 = offs[v], o1 = offs[v + 1];
  float a0 = 0.f, a1 = 0.f, a2 = 0.f, a3 = 0.f;
  int i = o0;
  for (; i + 8 <= o1; i += 8) {
    ushort4 q[8];
#pragma unroll
    for (int t = 0; t < 8; ++t)
      q[t] = *(const ushort4*)&z1b[(long)csr[i + t] * 512 + 256 + c];
#pragma unroll
    for (int t = 0; t < 8; ++t) {
      a0 += bf2f(q[t].x); a1 += bf2f(q[t].y);
      a2 += bf2f(q[t].z); a3 += bf2f(q[t].w);
    }
  }
  if (i + 4 <= o1) {
    ushort4 q[4];
#pragma unroll
    for (int t = 0; t < 4; ++t)
      q[t] = *(const ushort4*)&z1b[(long)csr[i + t] * 512 + 256 + c];
#pragma unroll
    for (int t = 0; t < 4; ++t) {
      a0 += bf2f(q[t].x); a1 += bf2f(q[t].y);
      a2 += bf2f(q[t].z); a3 += bf2f(q[t].w);
    }
    i += 4;
  }
  for (; i < o1; ++i) {
    ushort4 q = *(const ushort4*)&z1b[(long)csr[i] * 512 + 256 + c];
    a0 += bf2f(q.x); a1 += bf2f(q.y); a2 += bf2f(q.z); a3 += bf2f(q.w);
  }
  const float w = invdeg[v];
  ushort4 sf = *(const ushort4*)&z1b[(long)v * 512 + c];
  float4 bb = *(const float4*)&b1[c];
  ushort4 o;
  o.x = f2bf(fmaxf(bf2f(sf.x) + a0 * w + bb.x, 0.f));
  o.y = f2bf(fmaxf(bf2f(sf.y) + a1 * w + bb.y, 0.f));
  o.z = f2bf(fmaxf(bf2f(sf.z) + a2 * w + bb.z, 0.f));
  o.w = f2bf(fmaxf(bf2f(sf.w) + a3 * w + bb.w, 0.f));
  *(ushort4*)&h1b[(long)v * 256 + c] = o;
}

// h2 = z2_self + mean(z2_neigh) + b2 -> bf16 [N,64]
// one node per wave; half-wave = even edges, half-wave = odd edges;
// lane owns 2 channels (u32 loads); shfl_xor(32) merges the halves.
__global__ __launch_bounds__(256) void k_agg2(const u16* __restrict__ z2b,
                                              const int* __restrict__ csr,
                                              const int* __restrict__ offs,
                                              const float* __restrict__ invdeg,
                                              const float* __restrict__ b2,
                                              u16* __restrict__ h2b) {
  const int v    = blockIdx.x * 4 + (threadIdx.x >> 6);
  const int lane = threadIdx.x & 63;
  const int half = lane >> 5;
  const int c    = (lane & 31) * 2;
  const int o0 = offs[v], o1 = offs[v + 1];
  float a0 = 0.f, a1 = 0.f;
  int i = o0 + half;
  for (; i + 6 < o1; i += 8) {               // 4 iterations in flight per half
    u32 q0 = *(const u32*)&z2b[(long)csr[i]     * 128 + 64 + c];
    u32 q1 = *(const u32*)&z2b[(long)csr[i + 2] * 128 + 64 + c];
    u32 q2 = *(const u32*)&z2b[(long)csr[i + 4] * 128 + 64 + c];
    u32 q3 = *(const u32*)&z2b[(long)csr[i + 6] * 128 + 64 + c];
    a0 += (bf2f((u16)q0) + bf2f((u16)q1)) + (bf2f((u16)q2) + bf2f((u16)q3));
    a1 += (bf2f((u16)(q0 >> 16)) + bf2f((u16)(q1 >> 16))) +
          (bf2f((u16)(q2 >> 16)) + bf2f((u16)(q3 >> 16)));
  }
  for (; i < o1; i += 2) {
    const u32 q = *(const u32*)&z2b[(long)csr[i] * 128 + 64 + c];
    a0 += bf2f((u16)q);
    a1 += bf2f((u16)(q >> 16));
  }
  a0 += __shfl_xor(a0, 32);
  a1 += __shfl_xor(a1, 32);
  if (half == 0) {
    const float w = invdeg[v];
    const u32 sq = *(const u32*)&z2b[(long)v * 128 + c];
    float h0 = bf2f((u16)sq) + a0 * w + b2[c];
    float h1 = bf2f((u16)(sq >> 16)) + a1 * w + b2[c + 1];
    u32 o = (u32)f2bf(h0) | ((u32)f2bf(h1) << 16);
    *(u32*)&h2b[(long)v * 64 + c] = o;
  }
}

// ------------------------------------------------------------- edge scoring
// UV stored bf16 [N,128]. One edge per wave: lanes 0-31 load U[s] (2ch/lane),
// lanes 32-63 load V[d]; shfl_xor(32) combines; 32-lane tree reduce.
__global__ __launch_bounds__(256) void k_edge(const u16* __restrict__ UVb,
                                              const int* __restrict__ ps,
                                              const int* __restrict__ pd,
                                              const int* __restrict__ ns,
                                              const int* __restrict__ nd,
                                              const float* __restrict__ bp1,
                                              const float* __restrict__ Wp2,
                                              const float* __restrict__ bp2,
                                              float* __restrict__ out) {
  const int g    = blockIdx.x * 4 + (threadIdx.x >> 6);   // edge id
  const int lane = threadIdx.x & 63;
  const int half = lane >> 5;
  const int l    = lane & 31;
  int s, d;
  if (g < EPOS) { s = ps[g]; d = pd[g]; }
  else          { s = ns[g - EPOS]; d = nd[g - EPOS]; }
  const int node = half ? d : s;
  const u32 q = *(const u32*)&UVb[(long)node * 128 + half * 64 + 2 * l];
  float t0 = bf2f((u16)q), t1 = bf2f((u16)(q >> 16));
  t0 += __shfl_xor(t0, 32);
  t1 += __shfl_xor(t1, 32);
  const float2 bb = *(const float2*)&bp1[2 * l];
  const float2 ww = *(const float2*)&Wp2[2 * l];
  float p = fmaxf(t0 + bb.x, 0.f) * ww.x + fmaxf(t1 + bb.y, 0.f) * ww.y;
#pragma unroll
  for (int off = 16; off > 0; off >>= 1) p += __shfl_xor(p, off);
  if (lane == 0) out[g] = p + bp2[0];
}

// ---------------------------------------------------------------- launcher
extern "C" void kernel_launch(void* const* d_in, const int* in_sizes, int n_in,
                              void* d_out, int out_size, void* d_ws, size_t ws_size,
                              hipStream_t stream) {
  const float* x   = (const float*)d_in[0];
  const int*   src = (const int*)d_in[1];
  const int*   dst = (const int*)d_in[2];
  const int*   ps  = (const int*)d_in[3];
  const int*   pd  = (const int*)d_in[4];
  const int*   ns  = (const int*)d_in[5];
  const int*   nd  = (const int*)d_in[6];
  const float* Ws1 = (const float*)d_in[7];
  const float* Wn1 = (const float*)d_in[8];
  const float* b1  = (const float*)d_in[9];
  const float* Ws2 = (const float*)d_in[10];
  const float* Wn2 = (const float*)d_in[11];
  const float* b2  = (const float*)d_in[12];
  const float* Wp1 = (const float*)d_in[13];
  const float* bp1 = (const float*)d_in[14];
  const float* Wp2 = (const float*)d_in[15];
  const float* bp2 = (const float*)d_in[16];
  float* out = (float*)d_out;

  // workspace layout (~211 MB), regions reused across phases:
  //  region A [0, 102.4MB):   xb (GEMM1 in) -> h1b (+0), UVb (+51.2MB, bf16)
  //  region B [102.4, 204.8): epos (CSR build) -> z1b -> z2b (+0), h2b (+25.6MB)
  //  region C [204.8, ~211):  W1t, W2t, Wpt, deg, offs, invdeg, bsum, csr
  char* ws = (char*)d_ws;
  const size_t RB = 102400000;
  const size_t RC = 204800000;
  u16*   xb  = (u16*)(ws);
  u16*   h1b = (u16*)(ws);                    // alias: xb dead after GEMM1
  u16*   UVb = (u16*)(ws + 51200000);
  int*   epos= (int*)(ws + RB);               // dead after k_fill
  u16*   z1b = (u16*)(ws + RB);
  u16*   z2b = (u16*)(ws + RB);               // alias: z1b dead after agg1
  u16*   h2b = (u16*)(ws + RB + 25600000);
  size_t o = RC;
  u16*   W1t = (u16*)(ws + o); o += 524288;
  u16*   W2t = (u16*)(ws + o); o += 65536;
  u16*   Wpt = (u16*)(ws + o); o += 16384;
  int*   deg = (int*)(ws + o); o += 400128;
  int*   offs= (int*)(ws + o); o += 400128;
  float* idg = (float*)(ws + o); o += 400128;
  int*   bsum= (int*)(ws + o); o += 2048;
  int*   csr = (int*)(ws + o); o += 4000000;
  (void)ws_size; (void)in_sizes; (void)n_in; (void)out_size;

  hipMemsetAsync(deg, 0, 400128, stream);

  k_prep<<<30091, 256, 0, stream>>>(x, xb, dst, deg, epos,
                                    Ws1, Wn1, W1t, Ws2, Wn2, W2t, Wp1, Wpt);
  k_scan_a<<<NSB, 256, 0, stream>>>(deg, bsum);
  k_scan_b<<<1, 512, 0, stream>>>(bsum);
  k_scan_c<<<NSB, 256, 0, stream>>>(deg, bsum, offs, idg);
  k_fill<<<3907, 256, 0, stream>>>(src, dst, offs, epos, csr);

  gemm_bt<false, true><<<3128, 256, 0, stream>>>(xb, W1t, z1b, N_NODES, 512, 512);
  k_agg1<<<25000, 256, 0, stream>>>(z1b, csr, offs, idg, b1, h1b);
  gemm_bt<false, false><<<dim3(1, 782), 256, 0, stream>>>(h1b, W2t, z2b, N_NODES, 128, 256);
  k_agg2<<<25000, 256, 0, stream>>>(z2b, csr, offs, idg, b2, h2b);
  gemm_bt<false, false><<<dim3(1, 782), 256, 0, stream>>>(h2b, Wpt, UVb, N_NODES, 128, 64);
  k_edge<<<100000, 256, 0, stream>>>(UVb, ps, pd, ns, nd, bp1, Wp2, bp2, out);
}

// Round 5
// 705.852 us; speedup vs baseline: 1.6234x; 1.0143x over previous
//
#include <hip/hip_runtime.h>
#include <hip/hip_bf16.h>

// DoubleSAGE link predictor, restructured:
//   z1 = x @ [W_self1 | W_neigh1]          (f32-A bf16 MFMA GEMM, N=512)
//   h1 = relu(z1_self + CSR-mean(z1_neigh) + b1)
//   z2 = h1 @ [W_self2 | W_neigh2]         (N=128)
//   h2 = z2_self + CSR-mean(z2_neigh) + b2
//   UV = h2 @ [Wp1_top | Wp1_bot]          (N=128, bf16 out)
//   score(s,d) = relu(UV[s][:64] + UV[d][64:] + bp1) . Wp2 + bp2
// CSR built per-call (atomic histogram + 3-phase scan + non-atomic fill).
// GEMM1 converts x f32->bf16 during A reg-staging (no separate convert pass);
// bijective XCD-chunked swizzle (3128 = 8*391) for A-panel L2 reuse.

#define N_NODES 100000
#define N_EDGES 1000000
#define EPOS    200000
#define NSB     391        // ceil(N_NODES/256) scan blocks

typedef unsigned short u16;
typedef unsigned int   u32;

typedef __bf16 bf16x8 __attribute__((ext_vector_type(8)));
typedef float  f32x4  __attribute__((ext_vector_type(4)));
typedef u16    u16x8  __attribute__((ext_vector_type(8)));

__device__ __forceinline__ u16 f2bf(float f) {
  u32 u = __float_as_uint(f);
  u32 r = (u + 0x7fffu + ((u >> 16) & 1u)) >> 16;   // RNE
  return (u16)r;
}
__device__ __forceinline__ float bf2f(u16 h) {
  return __uint_as_float(((u32)h) << 16);
}
__device__ __forceinline__ u16x8 cvt8(float4 lo, float4 hi) {
  u16x8 o;
  o[0] = f2bf(lo.x); o[1] = f2bf(lo.y); o[2] = f2bf(lo.z); o[3] = f2bf(lo.w);
  o[4] = f2bf(hi.x); o[5] = f2bf(hi.y); o[6] = f2bf(hi.z); o[7] = f2bf(hi.w);
  return o;
}

__device__ __forceinline__ void gl_lds16(const void* g, void* l) {
  __builtin_amdgcn_global_load_lds(
      (const __attribute__((address_space(1))) void*)g,
      (__attribute__((address_space(3))) void*)l, 16, 0, 0);
}

// ------------------------------------------------- prep (hist + W repacks)
// blocks [0,3907):      deg histogram + epos    (1 edge/thread)
// [3907,4931):          W1t repack              (512x512)
// [4931,5059):          W2t repack              (128x256)
// [5059,5091):          Wpt repack              (128x64)
__global__ __launch_bounds__(256) void k_prep(
    const int* __restrict__ dst, int* __restrict__ deg, int* __restrict__ epos,
    const float* __restrict__ Ws1, const float* __restrict__ Wn1, u16* __restrict__ W1t,
    const float* __restrict__ Ws2, const float* __restrict__ Wn2, u16* __restrict__ W2t,
    const float* __restrict__ Wp1, u16* __restrict__ Wpt) {
  const int bid = blockIdx.x;
  const int tid = threadIdx.x;
  if (bid < 3907) {
    int e = bid * 256 + tid;
    if (e < N_EDGES) epos[e] = atomicAdd(&deg[dst[e]], 1);
  } else if (bid < 4931) {
    int idx = (bid - 3907) * 256 + tid;       // < 512*512
    int j = idx >> 9, k = idx & 511;
    float v = (j < 256) ? Ws1[k * 256 + j] : Wn1[k * 256 + (j - 256)];
    W1t[idx] = f2bf(v);
  } else if (bid < 5059) {
    int idx = (bid - 4931) * 256 + tid;       // < 128*256
    int j = idx >> 8, k = idx & 255;
    float v = (j < 64) ? Ws2[k * 64 + j] : Wn2[k * 64 + (j - 64)];
    W2t[idx] = f2bf(v);
  } else {
    int idx = (bid - 5059) * 256 + tid;       // < 128*64
    int j = idx >> 6, k = idx & 63;
    float v = (j < 64) ? Wp1[k * 64 + j] : Wp1[(64 + k) * 64 + (j - 64)];
    Wpt[idx] = f2bf(v);
  }
}

// ---------------------------------------------------------------- CSR scan
__global__ __launch_bounds__(256) void k_scan_a(const int* __restrict__ deg,
                                                int* __restrict__ bsum) {
  __shared__ int s[256];
  int i = blockIdx.x * 256 + threadIdx.x;
  s[threadIdx.x] = (i < N_NODES) ? deg[i] : 0;
  __syncthreads();
  for (int off = 128; off > 0; off >>= 1) {
    if (threadIdx.x < off) s[threadIdx.x] += s[threadIdx.x + off];
    __syncthreads();
  }
  if (threadIdx.x == 0) bsum[blockIdx.x] = s[0];
}

__global__ __launch_bounds__(512) void k_scan_b(int* __restrict__ bsum) {
  __shared__ int s[512];
  const int t = threadIdx.x;
  int v = (t < NSB) ? bsum[t] : 0;
  s[t] = v;
  __syncthreads();
  for (int off = 1; off < 512; off <<= 1) {
    int w = (t >= off) ? s[t - off] : 0;
    __syncthreads();
    s[t] += w;
    __syncthreads();
  }
  if (t < NSB) bsum[t] = s[t] - v;   // exclusive block base
}

__global__ __launch_bounds__(256) void k_scan_c(const int* __restrict__ deg,
                                                const int* __restrict__ bsum,
                                                int* __restrict__ offs,
                                                float* __restrict__ invdeg) {
  __shared__ int s[256];
  const int t = threadIdx.x;
  const int i = blockIdx.x * 256 + t;
  const int d = (i < N_NODES) ? deg[i] : 0;
  s[t] = d;
  __syncthreads();
  for (int off = 1; off < 256; off <<= 1) {
    int w = (t >= off) ? s[t - off] : 0;
    __syncthreads();
    s[t] += w;
    __syncthreads();
  }
  if (i < N_NODES) {
    const int base = bsum[blockIdx.x];
    offs[i] = base + s[t] - d;
    invdeg[i] = 1.0f / (float)(d > 0 ? d : 1);
    if (i == N_NODES - 1) offs[N_NODES] = base + s[t];
  }
}

__global__ void k_fill(const int* __restrict__ src, const int* __restrict__ dst,
                       const int* __restrict__ offs, const int* __restrict__ epos,
                       int* __restrict__ csr) {
  int i = blockIdx.x * 256 + threadIdx.x;
  if (i < N_EDGES) csr[offs[dst[i]] + epos[i]] = src[i];
}

// -------------------------------------------------------- GEMM1 (f32 A input)
// z1[M,512] = x[M,512] @ W1t[512,512]^T, A converted f32->bf16 during staging.
// 128x128 tile, 4 waves, BK=32, dbuf LDS; A reg-staged (T14 split: loads
// issued before MFMA block, cvt+ds_write after), B via global_load_lds.
// 1-D grid 3128 = 8*391, bijective XCD-chunked (bm,bn) swizzle.
__global__ __launch_bounds__(256) void gemm1_f32(const float* __restrict__ A,
                                                 const u16* __restrict__ Bt,
                                                 u16* __restrict__ C, int M) {
  const int K = 512, N = 512;
  __shared__ u16 As[2][4096];
  __shared__ u16 Bs[2][4096];
  const int tid  = threadIdx.x;
  const int lane = tid & 63;
  const int wid  = tid >> 6;
  const int wr   = wid >> 1, wc = wid & 1;
  const int d    = blockIdx.x;                // 3128 = 8 * 391
  const int s    = (d & 7) * 391 + (d >> 3);  // XCD-chunked, bijective
  const int bm0  = (s >> 2) * 128;
  const int bn0  = (s & 3) * 128;

  const int sr = tid >> 2;          // staging row 0..63 (and +64)
  const int sc = (tid & 3) * 8;     // staging col (element units)
  const float* pa0 = A + (long)min(bm0 + sr,      M - 1) * K + sc;
  const float* pa1 = A + (long)min(bm0 + sr + 64, M - 1) * K + sc;
  const u16*   pb0 = Bt + (long)(bn0 + sr)      * K + sc;
  const u16*   pb1 = Bt + (long)(bn0 + sr + 64) * K + sc;
  const int lw = wid * 512;         // wave-uniform LDS base (u16 units)

  f32x4 acc[4][4];
#pragma unroll
  for (int i = 0; i < 4; ++i)
#pragma unroll
    for (int j = 0; j < 4; ++j) {
      f32x4 z = {0.f, 0.f, 0.f, 0.f};
      acc[i][j] = z;
    }

  float4 r00, r01, r10, r11;
#define LOADA(kk) do { const int k0_ = (kk) << 5;                         \
    r00 = *(const float4*)(pa0 + k0_); r01 = *(const float4*)(pa0 + k0_ + 4); \
    r10 = *(const float4*)(pa1 + k0_); r11 = *(const float4*)(pa1 + k0_ + 4); } while (0)
#define STAGEB(buf, kk) do { const int k0_ = (kk) << 5;                   \
    gl_lds16(pb0 + k0_, &Bs[buf][lw]);                                    \
    gl_lds16(pb1 + k0_, &Bs[buf][2048 + lw]); } while (0)
#define CVW(buf) do {                                                     \
    *(u16x8*)&As[buf][sr * 32 + sc]        = cvt8(r00, r01);              \
    *(u16x8*)&As[buf][(sr + 64) * 32 + sc] = cvt8(r10, r11); } while (0)

  LOADA(0); STAGEB(0, 0); CVW(0);
  __syncthreads();                   // drains vmcnt+lgkmcnt
  int cur = 0;
  const int nk = K >> 5;             // 16
  for (int kk = 0; kk < nk; ++kk) {
    if (kk + 1 < nk) { LOADA(kk + 1); STAGEB(cur ^ 1, kk + 1); }  // in flight
    bf16x8 af[4], bfr[4];
#pragma unroll
    for (int mi = 0; mi < 4; ++mi)
      af[mi] = *reinterpret_cast<const bf16x8*>(
          &As[cur][(wr * 64 + mi * 16 + (lane & 15)) * 32 + ((lane >> 4) * 8)]);
#pragma unroll
    for (int ni = 0; ni < 4; ++ni)
      bfr[ni] = *reinterpret_cast<const bf16x8*>(
          &Bs[cur][(wc * 64 + ni * 16 + (lane & 15)) * 32 + ((lane >> 4) * 8)]);
#pragma unroll
    for (int mi = 0; mi < 4; ++mi)
#pragma unroll
      for (int ni = 0; ni < 4; ++ni)
        acc[mi][ni] = __builtin_amdgcn_mfma_f32_16x16x32_bf16(
            af[mi], bfr[ni], acc[mi][ni], 0, 0, 0);
    if (kk + 1 < nk) CVW(cur ^ 1);   // write-late: waits only A-loads
    __syncthreads();
    cur ^= 1;
  }
#undef LOADA
#undef STAGEB
#undef CVW

  // epilogue: C layout col = lane&15, row = (lane>>4)*4 + e   [m89-verified]
  const int colb = bn0 + wc * 64 + (lane & 15);
  const int rowb = bm0 + wr * 64 + ((lane >> 4) * 4);
#pragma unroll
  for (int mi = 0; mi < 4; ++mi)
#pragma unroll
    for (int ni = 0; ni < 4; ++ni) {
      const int col = colb + ni * 16;
#pragma unroll
      for (int e = 0; e < 4; ++e) {
        const int row = rowb + mi * 16 + e;
        if (row < M) C[(long)row * N + col] = f2bf(acc[mi][ni][e]);
      }
    }
}

// ------------------------------------------------------------- bf16 MFMA GEMM
// C[M,N] = A[M,K] @ Bt[N,K]^T (both bf16). 128x128 tile, 4 waves, BK=32,
// dbuf LDS via global_load_lds, 2-phase schedule. Used for GEMM2/GEMM3.
__global__ __launch_bounds__(256) void gemm_bt(const u16* __restrict__ A,
                                               const u16* __restrict__ Bt,
                                               u16* __restrict__ C,
                                               int M, int N, int K) {
  __shared__ u16 As[2][4096];
  __shared__ u16 Bs[2][4096];
  const int tid  = threadIdx.x;
  const int lane = tid & 63;
  const int wid  = tid >> 6;
  const int wr   = wid >> 1, wc = wid & 1;
  const int bm0  = blockIdx.y * 128;
  const int bn0  = blockIdx.x * 128;

  const int sr = tid >> 2;
  const int sc = (tid & 3) * 8;
  const u16* pa0 = A  + (long)min(bm0 + sr,      M - 1) * K + sc;
  const u16* pa1 = A  + (long)min(bm0 + sr + 64, M - 1) * K + sc;
  const u16* pb0 = Bt + (long)(bn0 + sr)      * K + sc;
  const u16* pb1 = Bt + (long)(bn0 + sr + 64) * K + sc;
  const int lw = wid * 512;

  f32x4 acc[4][4];
#pragma unroll
  for (int i = 0; i < 4; ++i)
#pragma unroll
    for (int j = 0; j < 4; ++j) {
      f32x4 z = {0.f, 0.f, 0.f, 0.f};
      acc[i][j] = z;
    }

  const int nk = K >> 5;
#define STAGE(buf, kk) do { const int k0_ = (kk) << 5;                    \
    gl_lds16(pa0 + k0_, &As[buf][lw]);                                    \
    gl_lds16(pa1 + k0_, &As[buf][2048 + lw]);                             \
    gl_lds16(pb0 + k0_, &Bs[buf][lw]);                                    \
    gl_lds16(pb1 + k0_, &Bs[buf][2048 + lw]); } while (0)

  STAGE(0, 0);
  __syncthreads();
  int cur = 0;
  for (int kk = 0; kk < nk; ++kk) {
    if (kk + 1 < nk) STAGE(cur ^ 1, kk + 1);
    bf16x8 af[4], bfr[4];
#pragma unroll
    for (int mi = 0; mi < 4; ++mi)
      af[mi] = *reinterpret_cast<const bf16x8*>(
          &As[cur][(wr * 64 + mi * 16 + (lane & 15)) * 32 + ((lane >> 4) * 8)]);
#pragma unroll
    for (int ni = 0; ni < 4; ++ni)
      bfr[ni] = *reinterpret_cast<const bf16x8*>(
          &Bs[cur][(wc * 64 + ni * 16 + (lane & 15)) * 32 + ((lane >> 4) * 8)]);
#pragma unroll
    for (int mi = 0; mi < 4; ++mi)
#pragma unroll
      for (int ni = 0; ni < 4; ++ni)
        acc[mi][ni] = __builtin_amdgcn_mfma_f32_16x16x32_bf16(
            af[mi], bfr[ni], acc[mi][ni], 0, 0, 0);
    __syncthreads();
    cur ^= 1;
  }
#undef STAGE

  const int colb = bn0 + wc * 64 + (lane & 15);
  const int rowb = bm0 + wr * 64 + ((lane >> 4) * 4);
#pragma unroll
  for (int mi = 0; mi < 4; ++mi)
#pragma unroll
    for (int ni = 0; ni < 4; ++ni) {
      const int col = colb + ni * 16;
#pragma unroll
      for (int e = 0; e < 4; ++e) {
        const int row = rowb + mi * 16 + e;
        if (row < M) C[(long)row * N + col] = f2bf(acc[mi][ni][e]);
      }
    }
}

// ------------------------------------------------------------- aggregation
// h1 = relu(z1_self + mean(z1_neigh) + b1) -> bf16 [N,256]
// one node per wave; half-wave per edge (lane owns 8 ch = ushort8 16B load);
// 4-deep unroll = 8 edges in flight per wave; shfl_xor(32) merges halves.
__global__ __launch_bounds__(256) void k_agg1(const u16* __restrict__ z1b,
                                              const int* __restrict__ csr,
                                              const int* __restrict__ offs,
                                              const float* __restrict__ invdeg,
                                              const float* __restrict__ b1,
                                              u16* __restrict__ h1b) {
  const int v    = blockIdx.x * 4 + (threadIdx.x >> 6);
  const int lane = threadIdx.x & 63;
  const int half = lane >> 5;
  const int c    = (lane & 31) * 8;           // channel base
  const int o0 = offs[v], o1 = offs[v + 1];
  float a[8];
#pragma unroll
  for (int e = 0; e < 8; ++e) a[e] = 0.f;
  int i = o0 + half;
  for (; i + 6 < o1; i += 8) {
    u16x8 q0 = *(const u16x8*)&z1b[(long)csr[i]     * 512 + 256 + c];
    u16x8 q1 = *(const u16x8*)&z1b[(long)csr[i + 2] * 512 + 256 + c];
    u16x8 q2 = *(const u16x8*)&z1b[(long)csr[i + 4] * 512 + 256 + c];
    u16x8 q3 = *(const u16x8*)&z1b[(long)csr[i + 6] * 512 + 256 + c];
#pragma unroll
    for (int e = 0; e < 8; ++e)
      a[e] += (bf2f(q0[e]) + bf2f(q1[e])) + (bf2f(q2[e]) + bf2f(q3[e]));
  }
  for (; i < o1; i += 2) {
    u16x8 q = *(const u16x8*)&z1b[(long)csr[i] * 512 + 256 + c];
#pragma unroll
    for (int e = 0; e < 8; ++e) a[e] += bf2f(q[e]);
  }
#pragma unroll
  for (int e = 0; e < 8; ++e) a[e] += __shfl_xor(a[e], 32);
  if (half == 0) {
    const float w = invdeg[v];
    u16x8 sf = *(const u16x8*)&z1b[(long)v * 512 + c];
    float4 bb0 = *(const float4*)&b1[c];
    float4 bb1 = *(const float4*)&b1[c + 4];
    float bb[8] = {bb0.x, bb0.y, bb0.z, bb0.w, bb1.x, bb1.y, bb1.z, bb1.w};
    u16x8 o;
#pragma unroll
    for (int e = 0; e < 8; ++e)
      o[e] = f2bf(fmaxf(bf2f(sf[e]) + a[e] * w + bb[e], 0.f));
    *(u16x8*)&h1b[(long)v * 256 + c] = o;
  }
}

// h2 = z2_self + mean(z2_neigh) + b2 -> bf16 [N,64]
__global__ __launch_bounds__(256) void k_agg2(const u16* __restrict__ z2b,
                                              const int* __restrict__ csr,
                                              const int* __restrict__ offs,
                                              const float* __restrict__ invdeg,
                                              const float* __restrict__ b2,
                                              u16* __restrict__ h2b) {
  const int v    = blockIdx.x * 4 + (threadIdx.x >> 6);
  const int lane = threadIdx.x & 63;
  const int half = lane >> 5;
  const int c    = (lane & 31) * 2;
  const int o0 = offs[v], o1 = offs[v + 1];
  float a0 = 0.f, a1 = 0.f;
  int i = o0 + half;
  for (; i + 6 < o1; i += 8) {               // 4 loads in flight per half
    u32 q0 = *(const u32*)&z2b[(long)csr[i]     * 128 + 64 + c];
    u32 q1 = *(const u32*)&z2b[(long)csr[i + 2] * 128 + 64 + c];
    u32 q2 = *(const u32*)&z2b[(long)csr[i + 4] * 128 + 64 + c];
    u32 q3 = *(const u32*)&z2b[(long)csr[i + 6] * 128 + 64 + c];
    a0 += (bf2f((u16)q0) + bf2f((u16)q1)) + (bf2f((u16)q2) + bf2f((u16)q3));
    a1 += (bf2f((u16)(q0 >> 16)) + bf2f((u16)(q1 >> 16))) +
          (bf2f((u16)(q2 >> 16)) + bf2f((u16)(q3 >> 16)));
  }
  for (; i < o1; i += 2) {
    const u32 q = *(const u32*)&z2b[(long)csr[i] * 128 + 64 + c];
    a0 += bf2f((u16)q);
    a1 += bf2f((u16)(q >> 16));
  }
  a0 += __shfl_xor(a0, 32);
  a1 += __shfl_xor(a1, 32);
  if (half == 0) {
    const float w = invdeg[v];
    const u32 sq = *(const u32*)&z2b[(long)v * 128 + c];
    float h0 = bf2f((u16)sq) + a0 * w + b2[c];
    float h1 = bf2f((u16)(sq >> 16)) + a1 * w + b2[c + 1];
    u32 o = (u32)f2bf(h0) | ((u32)f2bf(h1) << 16);
    *(u32*)&h2b[(long)v * 64 + c] = o;
  }
}

// ------------------------------------------------------------- edge scoring
__global__ __launch_bounds__(256) void k_edge(const u16* __restrict__ UVb,
                                              const int* __restrict__ ps,
                                              const int* __restrict__ pd,
                                              const int* __restrict__ ns,
                                              const int* __restrict__ nd,
                                              const float* __restrict__ bp1,
                                              const float* __restrict__ Wp2,
                                              const float* __restrict__ bp2,
                                              float* __restrict__ out) {
  const int g    = blockIdx.x * 4 + (threadIdx.x >> 6);   // edge id
  const int lane = threadIdx.x & 63;
  const int half = lane >> 5;
  const int l    = lane & 31;
  int s, d;
  if (g < EPOS) { s = ps[g]; d = pd[g]; }
  else          { s = ns[g - EPOS]; d = nd[g - EPOS]; }
  const int node = half ? d : s;
  const u32 q = *(const u32*)&UVb[(long)node * 128 + half * 64 + 2 * l];
  float t0 = bf2f((u16)q), t1 = bf2f((u16)(q >> 16));
  t0 += __shfl_xor(t0, 32);
  t1 += __shfl_xor(t1, 32);
  const float2 bb = *(const float2*)&bp1[2 * l];
  const float2 ww = *(const float2*)&Wp2[2 * l];
  float p = fmaxf(t0 + bb.x, 0.f) * ww.x + fmaxf(t1 + bb.y, 0.f) * ww.y;
#pragma unroll
  for (int off = 16; off > 0; off >>= 1) p += __shfl_xor(p, off);
  if (lane == 0) out[g] = p + bp2[0];
}

// ---------------------------------------------------------------- launcher
extern "C" void kernel_launch(void* const* d_in, const int* in_sizes, int n_in,
                              void* d_out, int out_size, void* d_ws, size_t ws_size,
                              hipStream_t stream) {
  const float* x   = (const float*)d_in[0];
  const int*   src = (const int*)d_in[1];
  const int*   dst = (const int*)d_in[2];
  const int*   ps  = (const int*)d_in[3];
  const int*   pd  = (const int*)d_in[4];
  const int*   ns  = (const int*)d_in[5];
  const int*   nd  = (const int*)d_in[6];
  const float* Ws1 = (const float*)d_in[7];
  const float* Wn1 = (const float*)d_in[8];
  const float* b1  = (const float*)d_in[9];
  const float* Ws2 = (const float*)d_in[10];
  const float* Wn2 = (const float*)d_in[11];
  const float* b2  = (const float*)d_in[12];
  const float* Wp1 = (const float*)d_in[13];
  const float* bp1 = (const float*)d_in[14];
  const float* Wp2 = (const float*)d_in[15];
  const float* bp2 = (const float*)d_in[16];
  float* out = (float*)d_out;

  // workspace layout (~211 MB), regions reused across phases:
  //  region A [0, 102.4MB):   h1b (GEMM2 in), UVb (+51.2MB, bf16)
  //  region B [102.4, 204.8): epos (CSR build) -> z1b -> z2b (+0), h2b (+25.6MB)
  //  region C [204.8, ~211):  W1t, W2t, Wpt, deg, offs, invdeg, bsum, csr
  char* ws = (char*)d_ws;
  const size_t RB = 102400000;
  const size_t RC = 204800000;
  u16*   h1b = (u16*)(ws);
  u16*   UVb = (u16*)(ws + 51200000);
  int*   epos= (int*)(ws + RB);               // dead after k_fill
  u16*   z1b = (u16*)(ws + RB);
  u16*   z2b = (u16*)(ws + RB);               // alias: z1b dead after agg1
  u16*   h2b = (u16*)(ws + RB + 25600000);
  size_t o = RC;
  u16*   W1t = (u16*)(ws + o); o += 524288;
  u16*   W2t = (u16*)(ws + o); o += 65536;
  u16*   Wpt = (u16*)(ws + o); o += 16384;
  int*   deg = (int*)(ws + o); o += 400128;
  int*   offs= (int*)(ws + o); o += 400128;
  float* idg = (float*)(ws + o); o += 400128;
  int*   bsum= (int*)(ws + o); o += 2048;
  int*   csr = (int*)(ws + o); o += 4000000;
  (void)ws_size; (void)in_sizes; (void)n_in; (void)out_size;

  hipMemsetAsync(deg, 0, 400128, stream);

  k_prep<<<5091, 256, 0, stream>>>(dst, deg, epos,
                                   Ws1, Wn1, W1t, Ws2, Wn2, W2t, Wp1, Wpt);
  k_scan_a<<<NSB, 256, 0, stream>>>(deg, bsum);
  k_scan_b<<<1, 512, 0, stream>>>(bsum);
  k_scan_c<<<NSB, 256, 0, stream>>>(deg, bsum, offs, idg);
  k_fill<<<3907, 256, 0, stream>>>(src, dst, offs, epos, csr);

  gemm1_f32<<<3128, 256, 0, stream>>>(x, W1t, z1b, N_NODES);
  k_agg1<<<25000, 256, 0, stream>>>(z1b, csr, offs, idg, b1, h1b);
  gemm_bt<<<dim3(1, 782), 256, 0, stream>>>(h1b, W2t, z2b, N_NODES, 128, 256);
  k_agg2<<<25000, 256, 0, stream>>>(z2b, csr, offs, idg, b2, h2b);
  gemm_bt<<<dim3(1, 782), 256, 0, stream>>>(h2b, Wpt, UVb, N_NODES, 128, 64);
  k_edge<<<100000, 256, 0, stream>>>(UVb, ps, pd, ns, nd, bp1, Wp2, bp2, out);
}